// Round 14
// baseline (269.515 us; speedup 1.0000x reference)
//
#include <hip/hip_runtime.h>
#include <hip/hip_bf16.h>
#include <hip/hip_fp8.h>
#include <cstdint>
#include <cstddef>

#define B_ 4
#define L_ 4096
#define D_ 1024
#define FF_ 2048
#define ROWS (B_ * L_)   // 16384
#define EPS_ 1e-5f
#define CG 64            // conv chunks
#define CC 64            // conv chunk length (L_/CG)

typedef __attribute__((ext_vector_type(8))) __bf16 bf16x8;
typedef __attribute__((ext_vector_type(4))) float f32x4;
typedef __attribute__((ext_vector_type(4))) unsigned short us4;

__device__ __forceinline__ float bf2f(unsigned short u) {
  union { unsigned int i; float f; } v; v.i = ((unsigned int)u) << 16; return v.f;
}
__device__ __forceinline__ unsigned short f2bf(float f) {
  union { float f; unsigned int i; } v; v.f = f;
  unsigned int r = v.i + 0x7fffu + ((v.i >> 16) & 1u);
  return (unsigned short)(r >> 16);
}
__device__ __forceinline__ unsigned char f2fp8(float f) {
  __hip_fp8_e4m3 q(f);
  return *reinterpret_cast<unsigned char*>(&q);
}

// ---------------- weight transpose + cast: in [K,N] f32 -> out [N,K] bf16 ----
__global__ __launch_bounds__(256) void transpose_cast(
    const float* __restrict__ in, unsigned short* __restrict__ out, int K, int N) {
  __shared__ float tb[32][33];
  int n0 = blockIdx.x * 32, k0 = blockIdx.y * 32;
  int tx = threadIdx.x & 31, ty = threadIdx.x >> 5;  // 32 x 8
#pragma unroll
  for (int i = 0; i < 4; ++i) {
    int k = ty + i * 8;
    tb[k][tx] = in[(size_t)(k0 + k) * N + n0 + tx];
  }
  __syncthreads();
#pragma unroll
  for (int i = 0; i < 4; ++i) {
    int n = ty + i * 8;
    out[(size_t)(n0 + n) * K + k0 + tx] = f2bf(tb[tx][n]);
  }
}

// ---------------- weight transpose + cast fp8: [K,N] f32 -> [N,K] e4m3*scale -
__global__ __launch_bounds__(256) void transpose_cast_fp8(
    const float* __restrict__ in, unsigned char* __restrict__ out, int K, int N,
    float scale) {
  __shared__ float tb[32][33];
  int n0 = blockIdx.x * 32, k0 = blockIdx.y * 32;
  int tx = threadIdx.x & 31, ty = threadIdx.x >> 5;
#pragma unroll
  for (int i = 0; i < 4; ++i) {
    int k = ty + i * 8;
    tb[k][tx] = in[(size_t)(k0 + k) * N + n0 + tx];
  }
  __syncthreads();
#pragma unroll
  for (int i = 0; i < 4; ++i) {
    int n = ty + i * 8;
    out[(size_t)(n0 + n) * K + k0 + tx] = f2fp8(tb[tx][n] * scale);
  }
}

// ---------------- LN1: x -> xn bf16 (LayerNorm), xb bf16 (plain cast) --------
__global__ __launch_bounds__(256) void ln1_kernel(
    const float* __restrict__ x, const float* __restrict__ g, const float* __restrict__ b,
    unsigned short* __restrict__ xn, unsigned short* __restrict__ xb) {
  int row = blockIdx.x;
  int t = threadIdx.x;
  const float4* xr = (const float4*)(x + (size_t)row * D_);
  float4 v = xr[t];
  float s = v.x + v.y + v.z + v.w;
  float sq = v.x * v.x + v.y * v.y + v.z * v.z + v.w * v.w;
#pragma unroll
  for (int off = 32; off > 0; off >>= 1) {
    s += __shfl_down(s, off);
    sq += __shfl_down(sq, off);
  }
  __shared__ float ls[4], lq[4];
  int lane = t & 63, w = t >> 6;
  if (lane == 0) { ls[w] = s; lq[w] = sq; }
  __syncthreads();
  s = ls[0] + ls[1] + ls[2] + ls[3];
  sq = lq[0] + lq[1] + lq[2] + lq[3];
  float mean = s * (1.0f / D_);
  float var = sq * (1.0f / D_) - mean * mean;
  float rstd = rsqrtf(var + EPS_);
  float4 gv = ((const float4*)g)[t];
  float4 bv = ((const float4*)b)[t];
  us4 o, ob;
  o.x = f2bf((v.x - mean) * rstd * gv.x + bv.x);
  o.y = f2bf((v.y - mean) * rstd * gv.y + bv.y);
  o.z = f2bf((v.z - mean) * rstd * gv.z + bv.z);
  o.w = f2bf((v.w - mean) * rstd * gv.w + bv.w);
  ob.x = f2bf(v.x); ob.y = f2bf(v.y); ob.z = f2bf(v.z); ob.w = f2bf(v.w);
  ((us4*)(xn + (size_t)row * D_))[t] = o;
  ((us4*)(xb + (size_t)row * D_))[t] = ob;
}

// ---------------- conv pass 1: per-chunk local recurrence --------------------
__global__ __launch_bounds__(256) void conv_pass1(
    const unsigned short* __restrict__ xn, const float* __restrict__ ph_re,
    const float* __restrict__ ph_im, float2* __restrict__ rloc) {
  int d = blockIdx.x * 256 + threadIdx.x;
  int g = blockIdx.y, b = blockIdx.z;
  float re = ph_re[d], im = ph_im[d];
  float a = sqrtf(re * re + im * im);
  float sc = expf(-a) / a;
  float pr = re * sc, pi = im * sc;
  float rr = 0.f, ri = 0.f;
  const unsigned short* xp = xn + ((size_t)(b * L_ + g * CC)) * D_ + d;
#pragma unroll 8
  for (int l = 0; l < CC; ++l) {
    float xv = bf2f(xp[(size_t)l * D_]);
    float nr = pr * rr - pi * ri + xv;
    ri = pr * ri + pi * rr;
    rr = nr;
  }
  rloc[((size_t)(b * CG + g)) * D_ + d] = make_float2(rr, ri);
}

// ---------------- conv pass 2: scan over chunks (batch-8 prefetched) ---------
__global__ __launch_bounds__(256) void conv_pass2(
    const float* __restrict__ ph_re, const float* __restrict__ ph_im,
    const float2* __restrict__ rloc, float2* __restrict__ carry) {
  int idx = blockIdx.x * 256 + threadIdx.x;  // 0..B*D-1
  int b = idx >> 10, d = idx & (D_ - 1);
  float re = ph_re[d], im = ph_im[d];
  float a = sqrtf(re * re + im * im);
  float th = atan2f(im, re);
  float rho = expf(-a * (float)CC);
  float ang = th * (float)CC;
  float pcr = rho * cosf(ang), pci = rho * sinf(ang);
  float cr = 0.f, ci = 0.f;
  for (int g0 = 0; g0 < CG; g0 += 8) {
    float2 rl[8];
    float2 cw[8];
#pragma unroll
    for (int i = 0; i < 8; ++i)
      rl[i] = rloc[((size_t)(b * CG + g0 + i)) * D_ + d];
#pragma unroll
    for (int i = 0; i < 8; ++i) {
      cw[i] = make_float2(cr, ci);
      float nr = pcr * cr - pci * ci + rl[i].x;
      ci = pcr * ci + pci * cr + rl[i].y;
      cr = nr;
    }
#pragma unroll
    for (int i = 0; i < 8; ++i)
      carry[((size_t)(b * CG + g0 + i)) * D_ + d] = cw[i];
  }
}

// ---------------- conv pass 3: outputs -------------------------------------
__global__ __launch_bounds__(256) void conv_pass3(
    const unsigned short* __restrict__ xn,
    const float* __restrict__ ph_re, const float* __restrict__ ph_im,
    const float* __restrict__ phi_re, const float* __restrict__ phi_im,
    const float* __restrict__ lci_re, const float* __restrict__ lci_im,
    const float2* __restrict__ carry, unsigned short* __restrict__ cout) {
  int d = blockIdx.x * 256 + threadIdx.x;
  int g = blockIdx.y, b = blockIdx.z;
  float re = ph_re[d], im = ph_im[d];
  float a = sqrtf(re * re + im * im);
  float sc = expf(-a) / a;
  float pr = re * sc, pi = im * sc;
  float th = atan2f(im, re);
  int l0 = g * CC;
  float rho = expf(-a * (float)(l0 + 1));
  float ang = th * (float)(l0 + 1);
  float prr = rho * cosf(ang), pri = rho * sinf(ang);
  float fr = phi_re[d], fi = phi_im[d];
  float qr = lci_re[d], qi = lci_im[d];
  float2 cv = carry[((size_t)(b * CG + g)) * D_ + d];
  float rr = cv.x, ri = cv.y;
  const unsigned short* xp = xn + ((size_t)(b * L_ + l0)) * D_ + d;
  unsigned short* cp = cout + ((size_t)(b * L_ + l0)) * D_ + d;
#pragma unroll 4
  for (int l = 0; l < CC; ++l) {
    float xv = bf2f(xp[(size_t)l * D_]);
    float nr = pr * rr - pi * ri + xv;
    ri = pr * ri + pi * rr;
    rr = nr;
    float outv = fr * rr - fi * ri + qr * prr - qi * pri;  // Re(phi*r + lci*p)
    cp[(size_t)l * D_] = f2bf(outv);
    float pn = pr * prr - pi * pri;
    pri = pr * pri + pi * prr;
    prr = pn;
  }
}

// ---------------- LN2c: x3 = LN(x2 bf16) -> fp8 e4m3 ------------------------
__global__ __launch_bounds__(256) void ln2c_kernel(
    const unsigned short* __restrict__ x2, const float* __restrict__ g,
    const float* __restrict__ b, unsigned char* __restrict__ x3) {
  int row = blockIdx.x;
  int t = threadIdx.x;
  size_t base = (size_t)row * D_;
  us4 vb = ((const us4*)(x2 + base))[t];
  float4 v;
  v.x = bf2f(vb.x); v.y = bf2f(vb.y); v.z = bf2f(vb.z); v.w = bf2f(vb.w);
  float s = v.x + v.y + v.z + v.w;
  float sq = v.x * v.x + v.y * v.y + v.z * v.z + v.w * v.w;
#pragma unroll
  for (int off = 32; off > 0; off >>= 1) {
    s += __shfl_down(s, off);
    sq += __shfl_down(sq, off);
  }
  __shared__ float ls[4], lq[4];
  int lane = t & 63, w = t >> 6;
  if (lane == 0) { ls[w] = s; lq[w] = sq; }
  __syncthreads();
  s = ls[0] + ls[1] + ls[2] + ls[3];
  sq = lq[0] + lq[1] + lq[2] + lq[3];
  float mean = s * (1.0f / D_);
  float var = sq * (1.0f / D_) - mean * mean;
  float rstd = rsqrtf(var + EPS_);
  float4 gv = ((const float4*)g)[t];
  float4 bv = ((const float4*)b)[t];
  uchar4 o;
  o.x = f2fp8((v.x - mean) * rstd * gv.x + bv.x);
  o.y = f2fp8((v.y - mean) * rstd * gv.y + bv.y);
  o.z = f2fp8((v.z - mean) * rstd * gv.z + bv.z);
  o.w = f2fp8((v.w - mean) * rstd * gv.w + bv.w);
  ((uchar4*)(x3 + base))[t] = o;
}

// ============================================================================
__device__ __forceinline__ void gld_lds16(const void* gp, void* lp) {
  __builtin_amdgcn_global_load_lds(
      (const __attribute__((address_space(1))) unsigned int*)gp,
      (__attribute__((address_space(3))) unsigned int*)lp, 16, 0, 0);
}

#define PHASE_SYNC()                                         \
  __builtin_amdgcn_s_barrier();                              \
  asm volatile("s_waitcnt lgkmcnt(0)" ::: "memory");         \
  __builtin_amdgcn_sched_barrier(0);                         \
  __builtin_amdgcn_s_setprio(1);

#define PHASE_END()                                          \
  __builtin_amdgcn_s_setprio(0);

// ---------------- bf16 GEMM (R10 structure, proven): gemm1 only -------------
// BM=256, BN=128, BK=64, 8 waves (4Mx2N), ring-3 144KiB, 2 phases/tile,
// vmcnt(6) counted distance-2. Epilogue: x2 = gate*silu(.)+x (f32 x), bf16 out.
__global__ __launch_bounds__(512) void gemm_bt_gate(
    const unsigned short* __restrict__ A, const unsigned short* __restrict__ Bt,
    const float* __restrict__ bias,
    const unsigned short* __restrict__ gate, const float* __restrict__ xresf,
    unsigned short* __restrict__ Cv, int NB, int GROUP, int N, int K) {
  __shared__ unsigned short As[3][256 * 64];
  __shared__ unsigned short Bs[3][128 * 64];

  int nwg = gridDim.x;
  int xcd = blockIdx.x & 7;
  int lo = blockIdx.x >> 3;
  int q = nwg >> 3;
  int gsz = GROUP * NB;
  int g_ = lo / gsz, r_ = lo % gsz;
  int n_ = r_ / GROUP, ml = r_ - n_ * GROUP;
  int Mx = q / NB;
  int bm0 = (xcd * Mx + g_ * GROUP + ml) * 256;
  int bn0 = n_ * 128;

  int t = threadIdx.x;
  int lane = t & 63, w = t >> 6;
  int wr = w >> 1, wc = w & 1;
  int frr = lane & 15, cl = lane >> 4;
  int fx = frr & 7;
  int rA0 = wr * 64 + frr;
  int rB0 = wc * 64 + frr;
  int ko0 = (cl ^ fx) * 8;
  int ko1 = ((4 + cl) ^ fx) * 8;

  int nt = K >> 6;

  int tr = t >> 3;
  int jx = (t & 7) ^ (tr & 7);
  const unsigned short* pA = A + (size_t)(bm0 + tr) * K + jx * 8;
  const unsigned short* pB = Bt + (size_t)(bn0 + tr) * K + jx * 8;

  auto stA = [&](int kt2, int slot, int c) {
    gld_lds16(pA + (size_t)kt2 * 64 + (size_t)c * 64 * K, &As[slot][c * 4096 + t * 8]);
  };
  auto stB = [&](int kt2, int slot, int c) {
    gld_lds16(pB + (size_t)kt2 * 64 + (size_t)c * 64 * K, &Bs[slot][c * 4096 + t * 8]);
  };

  f32x4 acc[4][4] = {};

  stA(0, 0, 0); stA(0, 0, 1); stA(0, 0, 2); stA(0, 0, 3); stB(0, 0, 0); stB(0, 0, 1);
  stA(1, 1, 0); stA(1, 1, 1); stA(1, 1, 2); stA(1, 1, 3); stB(1, 1, 0); stB(1, 1, 1);
  asm volatile("s_waitcnt vmcnt(6)" ::: "memory");
  __builtin_amdgcn_s_barrier();

  int s = 0;
  for (int kt = 0; kt < nt; ++kt) {
    const unsigned short* as = As[s];
    const unsigned short* bs = Bs[s];
    int s2 = s + 2; if (s2 >= 3) s2 -= 3;
    bool p2 = kt + 2 < nt;

    bf16x8 a0[4], b0[4];
#pragma unroll
    for (int m = 0; m < 4; ++m) a0[m] = *(const bf16x8*)&as[(rA0 + m * 16) * 64 + ko0];
#pragma unroll
    for (int n = 0; n < 4; ++n) b0[n] = *(const bf16x8*)&bs[(rB0 + n * 16) * 64 + ko0];
    if (p2) { stA(kt + 2, s2, 0); stA(kt + 2, s2, 1); stB(kt + 2, s2, 0); }
    PHASE_SYNC();
#pragma unroll
    for (int m = 0; m < 4; ++m)
#pragma unroll
      for (int n = 0; n < 4; ++n)
        acc[m][n] = __builtin_amdgcn_mfma_f32_16x16x32_bf16(a0[m], b0[n], acc[m][n], 0, 0, 0);
    PHASE_END();
    __builtin_amdgcn_s_barrier();

    bf16x8 a1[4], b1[4];
#pragma unroll
    for (int m = 0; m < 4; ++m) a1[m] = *(const bf16x8*)&as[(rA0 + m * 16) * 64 + ko1];
#pragma unroll
    for (int n = 0; n < 4; ++n) b1[n] = *(const bf16x8*)&bs[(rB0 + n * 16) * 64 + ko1];
    if (p2) { stA(kt + 2, s2, 2); stA(kt + 2, s2, 3); stB(kt + 2, s2, 1); }
    PHASE_SYNC();
#pragma unroll
    for (int m = 0; m < 4; ++m)
#pragma unroll
      for (int n = 0; n < 4; ++n)
        acc[m][n] = __builtin_amdgcn_mfma_f32_16x16x32_bf16(a1[m], b1[n], acc[m][n], 0, 0, 0);
    PHASE_END();
    if (p2) { asm volatile("s_waitcnt vmcnt(6)" ::: "memory"); }
    else    { asm volatile("s_waitcnt vmcnt(0)" ::: "memory"); }
    __builtin_amdgcn_s_barrier();
    s += 1; if (s == 3) s = 0;
  }

#pragma unroll
  for (int m = 0; m < 4; ++m) {
#pragma unroll
    for (int n = 0; n < 4; ++n) {
#pragma unroll
      for (int r = 0; r < 4; ++r) {
        int row = bm0 + wr * 64 + m * 16 + cl * 4 + r;
        int col = bn0 + wc * 64 + n * 16 + frr;
        size_t o = (size_t)row * N + col;
        float v = acc[m][n][r] + bias[col];
        v = v / (1.0f + __expf(-v));
        v = bf2f(gate[o]) * v + xresf[o];
        Cv[o] = f2bf(v);
      }
    }
  }
}

// ---------------- fp8 GEMM: single-phase K-tile (R13 schedule, isolated) ----
// BM=256, BN=128, BK=64, 8 waves (4Mx2N), ring-3 = 72 KiB -> 2 blocks/CU.
// Per tile: [16 ds_read_b64][3 gld_lds stage(T+2)][lgkmcnt(0)+sched_barrier]
//           [setprio(1) 32 MFMA setprio(0)][vmcnt(3)][s_barrier]
// WAR: slot-s2 readers (tile T-1) lgkm-drained before T-1's end barrier,
// stage issues after it. RAW: vmcnt(3) at end of T => S(T+1) landed.
// OUT: 0=f32(+bf16 res), 1=fp8.
template <int SILU, int RESBF, int OUT_FP8>
__global__ __launch_bounds__(512, 4) void gemm_f8(
    const unsigned char* __restrict__ A, const unsigned char* __restrict__ Bt,
    const float* __restrict__ bias, const unsigned short* __restrict__ resb,
    float oscale, void* __restrict__ Cv, int NB, int GROUP, int N, int K) {
  __shared__ unsigned char As[3][256 * 64];  // 3 x 16 KiB
  __shared__ unsigned char Bs[3][128 * 64];  // 3 x 8 KiB

  int nwg = gridDim.x;
  int xcd = blockIdx.x & 7;
  int lo = blockIdx.x >> 3;
  int q = nwg >> 3;
  int gsz = GROUP * NB;
  int g_ = lo / gsz, r_ = lo % gsz;
  int n_ = r_ / GROUP, ml = r_ - n_ * GROUP;
  int Mx = q / NB;
  int bm0 = (xcd * Mx + g_ * GROUP + ml) * 256;
  int bn0 = n_ * 128;

  int t = threadIdx.x;
  int lane = t & 63, w = t >> 6;
  int wr = w >> 1, wc = w & 1;          // 4M x 2N
  int frr = lane & 15, cl = lane >> 4;  // row, k-chunk (0..3)
  int sw = (frr >> 1) & 3;              // swizzle key
  int rA0 = wr * 64 + frr;
  int rB0 = wc * 64 + frr;
  int ko0 = ((((cl >> 1) ^ sw) << 4) | ((cl & 1) << 3));
  int ko1 = (((((cl >> 1) + 2) ^ sw) << 4) | ((cl & 1) << 3));

  int nt = K >> 6;  // K-tiles of 64 fp8

  // staging: 128 rows/call; thread t -> row t>>2, physical 16B chunk t&3
  int tr = t >> 2;                      // 0..127
  int jc = (t & 3) ^ ((tr >> 1) & 3);   // logical 16B chunk to fetch
  const unsigned char* pA = A + (size_t)(bm0 + tr) * K + jc * 16;
  const unsigned char* pB = Bt + (size_t)(bn0 + tr) * K + jc * 16;

  auto stA = [&](int kt2, int slot, int c) {  // c=0: rows 0-127, c=1: 128-255
    gld_lds16(pA + (size_t)kt2 * 64 + (size_t)c * 128 * K, &As[slot][c * 8192 + t * 16]);
  };
  auto stB = [&](int kt2, int slot) {
    gld_lds16(pB + (size_t)kt2 * 64, &Bs[slot][t * 16]);
  };

  f32x4 acc[4][4] = {};

  // prologue: stage T0 (3), T1 (3); vmcnt(3) -> T0 landed
  stA(0, 0, 0); stA(0, 0, 1); stB(0, 0);
  stA(1, 1, 0); stA(1, 1, 1); stB(1, 1);
  asm volatile("s_waitcnt vmcnt(3)" ::: "memory");
  __builtin_amdgcn_s_barrier();

  int s = 0;
  for (int kt = 0; kt < nt; ++kt) {
    const unsigned char* as = As[s];
    const unsigned char* bs = Bs[s];
    int s2 = s + 2; if (s2 >= 3) s2 -= 3;
    bool p2 = kt + 2 < nt;

    long a0[4], b0[4], a1[4], b1[4];
#pragma unroll
    for (int m = 0; m < 4; ++m) a0[m] = *(const long*)&as[(rA0 + m * 16) * 64 + ko0];
#pragma unroll
    for (int n = 0; n < 4; ++n) b0[n] = *(const long*)&bs[(rB0 + n * 16) * 64 + ko0];
#pragma unroll
    for (int m = 0; m < 4; ++m) a1[m] = *(const long*)&as[(rA0 + m * 16) * 64 + ko1];
#pragma unroll
    for (int n = 0; n < 4; ++n) b1[n] = *(const long*)&bs[(rB0 + n * 16) * 64 + ko1];
    if (p2) { stA(kt + 2, s2, 0); stA(kt + 2, s2, 1); stB(kt + 2, s2); }

    asm volatile("s_waitcnt lgkmcnt(0)" ::: "memory");
    __builtin_amdgcn_sched_barrier(0);
    __builtin_amdgcn_s_setprio(1);
#pragma unroll
    for (int m = 0; m < 4; ++m)
#pragma unroll
      for (int n = 0; n < 4; ++n)
        acc[m][n] = __builtin_amdgcn_mfma_f32_16x16x32_fp8_fp8(a0[m], b0[n], acc[m][n], 0, 0, 0);
#pragma unroll
    for (int m = 0; m < 4; ++m)
#pragma unroll
      for (int n = 0; n < 4; ++n)
        acc[m][n] = __builtin_amdgcn_mfma_f32_16x16x32_fp8_fp8(a1[m], b1[n], acc[m][n], 0, 0, 0);
    __builtin_amdgcn_s_setprio(0);

    if (p2) { asm volatile("s_waitcnt vmcnt(3)" ::: "memory"); }
    else    { asm volatile("s_waitcnt vmcnt(0)" ::: "memory"); }
    __builtin_amdgcn_s_barrier();
    s += 1; if (s == 3) s = 0;
  }

  // epilogue (16x16 C layout: col=lane&15, row=(lane>>4)*4+reg)
#pragma unroll
  for (int m = 0; m < 4; ++m) {
#pragma unroll
    for (int n = 0; n < 4; ++n) {
#pragma unroll
      for (int r = 0; r < 4; ++r) {
        int row = bm0 + wr * 64 + m * 16 + cl * 4 + r;
        int col = bn0 + wc * 64 + n * 16 + frr;
        size_t o = (size_t)row * N + col;
        float v = acc[m][n][r] * oscale + bias[col];
        if (SILU) v = v / (1.0f + __expf(-v));
        if (RESBF) v += bf2f(resb[o]);
        if (OUT_FP8)
          ((unsigned char*)Cv)[o] = f2fp8(v);
        else
          ((float*)Cv)[o] = v;
      }
    }
  }
}

// ---------------------------------------------------------------------------
extern "C" void kernel_launch(void* const* d_in, const int* in_sizes, int n_in,
                              void* d_out, int out_size, void* d_ws, size_t ws_size,
                              hipStream_t stream) {
  const float* x      = (const float*)d_in[0];
  const float* ln_g   = (const float*)d_in[1];
  const float* ln_b   = (const float*)d_in[2];
  const float* fc_w   = (const float*)d_in[3];
  const float* fc_b   = (const float*)d_in[4];
  const float* w1     = (const float*)d_in[5];
  const float* b1     = (const float*)d_in[6];
  const float* w2     = (const float*)d_in[7];
  const float* b2     = (const float*)d_in[8];
  const float* ph_re  = (const float*)d_in[9];
  const float* ph_im  = (const float*)d_in[10];
  const float* phi_re = (const float*)d_in[11];
  const float* phi_im = (const float*)d_in[12];
  const float* lci_re = (const float*)d_in[13];
  const float* lci_im = (const float*)d_in[14];
  float* out = (float*)d_out;

  char* ws = (char*)d_ws;
  const size_t SZ_BF = (size_t)ROWS * D_ * 2;   // 32 MiB
  const size_t SZ_F8 = (size_t)ROWS * D_;       // 16 MiB
  unsigned short* xn_x2 = (unsigned short*)(ws);               // xn; then x2 bf16
  unsigned short* cbuf  = (unsigned short*)(ws + SZ_BF);       // conv out bf16
  unsigned short* xb    = (unsigned short*)(ws + 2 * SZ_BF);   // x bf16 (gemm1 A)
  unsigned char*  x3f8  = (unsigned char*)(ws + 3 * SZ_BF);    // x3 fp8 (16 MiB)
  unsigned char*  h1f8  = (unsigned char*)(ws + 3 * SZ_BF + SZ_F8);  // h1 fp8 (32 MiB)
  char* wp = ws + 3 * SZ_BF + SZ_F8 + (size_t)ROWS * FF_;
  unsigned short* fc_wt = (unsigned short*)(wp);                       // 2 MiB
  unsigned char*  w1t8  = (unsigned char*)(wp + (size_t)D_ * D_ * 2);  // 2 MiB
  unsigned char*  w2t8  = (unsigned char*)(wp + (size_t)D_ * D_ * 2 + (size_t)D_ * FF_);
  float2* rloc  = (float2*)(wp + (size_t)D_ * D_ * 2 + 2 * (size_t)D_ * FF_);
  float2* carry = rloc + (size_t)B_ * CG * D_;

  // weight prep
  transpose_cast<<<dim3(D_ / 32, D_ / 32), 256, 0, stream>>>(fc_w, fc_wt, D_, D_);
  transpose_cast_fp8<<<dim3(FF_ / 32, D_ / 32), 256, 0, stream>>>(w1, w1t8, D_, FF_, 32.0f);
  transpose_cast_fp8<<<dim3(D_ / 32, FF_ / 32), 256, 0, stream>>>(w2, w2t8, FF_, D_, 32.0f);

  // LN1: xn bf16 (conv input) + xb bf16 (gemm1 A)
  ln1_kernel<<<ROWS, 256, 0, stream>>>(x, ln_g, ln_b, xn_x2, xb);

  // conv (chunked scan)
  conv_pass1<<<dim3(D_ / 256, CG, B_), 256, 0, stream>>>(xn_x2, ph_re, ph_im, rloc);
  conv_pass2<<<dim3((B_ * D_) / 256), 256, 0, stream>>>(ph_re, ph_im, rloc, carry);
  conv_pass3<<<dim3(D_ / 256, CG, B_), 256, 0, stream>>>(xn_x2, ph_re, ph_im, phi_re, phi_im,
                                                         lci_re, lci_im, carry, cbuf);

  // x2 = c * silu(x @ fc_w + fc_b) + x   (bf16 gemm, bf16 out -> xn region)
  gemm_bt_gate<<<(ROWS / 256) * (D_ / 128), 512, 0, stream>>>(
      xb, fc_wt, fc_b, cbuf, x, xn_x2, D_ / 128, 4, D_, D_);

  // x3 = LN(x2) -> fp8
  ln2c_kernel<<<ROWS, 256, 0, stream>>>(xn_x2, ln_g, ln_b, x3f8);

  // h1 = silu(x3 @ (32*w1)/32 + b1) -> fp8   [fp8 gemm, single-phase]
  gemm_f8<1, 0, 1><<<(ROWS / 256) * (FF_ / 128), 512, 0, stream>>>(
      x3f8, w1t8, b1, nullptr, 1.0f / 32.0f, h1f8, FF_ / 128, 4, FF_, D_);

  // out = x2 + h1 @ (32*w2)/32 + b2   [fp8 gemm, f32 out]
  gemm_f8<0, 1, 0><<<(ROWS / 256) * (D_ / 128), 512, 0, stream>>>(
      h1f8, w2t8, b2, xn_x2, 1.0f / 32.0f, out, D_ / 128, 2, D_, FF_);
}

// Round 15
// 259.589 us; speedup vs baseline: 1.0382x; 1.0382x over previous
//
#include <hip/hip_runtime.h>
#include <hip/hip_bf16.h>
#include <hip/hip_fp8.h>
#include <cstdint>
#include <cstddef>

#define B_ 4
#define L_ 4096
#define D_ 1024
#define FF_ 2048
#define ROWS (B_ * L_)   // 16384
#define EPS_ 1e-5f
#define CG 64            // conv chunks
#define CC 64            // conv chunk length (L_/CG)

typedef __attribute__((ext_vector_type(8))) __bf16 bf16x8;
typedef __attribute__((ext_vector_type(4))) float f32x4;
typedef __attribute__((ext_vector_type(4))) unsigned short us4;
typedef __attribute__((ext_vector_type(2))) long l2;

__device__ __forceinline__ float bf2f(unsigned short u) {
  union { unsigned int i; float f; } v; v.i = ((unsigned int)u) << 16; return v.f;
}
__device__ __forceinline__ unsigned short f2bf(float f) {
  union { float f; unsigned int i; } v; v.f = f;
  unsigned int r = v.i + 0x7fffu + ((v.i >> 16) & 1u);
  return (unsigned short)(r >> 16);
}
__device__ __forceinline__ unsigned char f2fp8(float f) {
  __hip_fp8_e4m3 q(f);
  return *reinterpret_cast<unsigned char*>(&q);
}
// k-interleave permutation within 64-byte groups: phys block order {0,4,1,5,2,6,3,7}
// => 16B chunk c holds k-blocks {c, c+4}; one b128 read serves ks=0 AND ks=1.
__device__ __forceinline__ int ph64(int e) {  // e in [0,64)
  return (((e >> 3) & 3) << 4) | (((e >> 5) & 1) << 3) | (e & 7);
}

// ---------------- weight transpose + cast: in [K,N] f32 -> out [N,K] bf16 ----
__global__ __launch_bounds__(256) void transpose_cast(
    const float* __restrict__ in, unsigned short* __restrict__ out, int K, int N) {
  __shared__ float tb[32][33];
  int n0 = blockIdx.x * 32, k0 = blockIdx.y * 32;
  int tx = threadIdx.x & 31, ty = threadIdx.x >> 5;  // 32 x 8
#pragma unroll
  for (int i = 0; i < 4; ++i) {
    int k = ty + i * 8;
    tb[k][tx] = in[(size_t)(k0 + k) * N + n0 + tx];
  }
  __syncthreads();
#pragma unroll
  for (int i = 0; i < 4; ++i) {
    int n = ty + i * 8;
    out[(size_t)(n0 + n) * K + k0 + tx] = f2bf(tb[tx][n]);
  }
}

// -------- weight transpose + cast fp8 (k-interleaved): [K,N] -> [N,K] --------
__global__ __launch_bounds__(256) void transpose_cast_fp8(
    const float* __restrict__ in, unsigned char* __restrict__ out, int K, int N,
    float scale) {
  __shared__ float tb[32][33];
  int n0 = blockIdx.x * 32, k0 = blockIdx.y * 32;
  int tx = threadIdx.x & 31, ty = threadIdx.x >> 5;
#pragma unroll
  for (int i = 0; i < 4; ++i) {
    int k = ty + i * 8;
    tb[k][tx] = in[(size_t)(k0 + k) * N + n0 + tx];
  }
  __syncthreads();
#pragma unroll
  for (int i = 0; i < 4; ++i) {
    int n = ty + i * 8;
    int k = k0 + tx;
    size_t idx = (size_t)(n0 + n) * K + (k & ~63) + ph64(k & 63);
    out[idx] = f2fp8(tb[tx][n] * scale);
  }
}

// ---------------- LN1: x -> xn bf16 (LayerNorm), xb bf16 (plain cast) --------
__global__ __launch_bounds__(256) void ln1_kernel(
    const float* __restrict__ x, const float* __restrict__ g, const float* __restrict__ b,
    unsigned short* __restrict__ xn, unsigned short* __restrict__ xb) {
  int row = blockIdx.x;
  int t = threadIdx.x;
  const float4* xr = (const float4*)(x + (size_t)row * D_);
  float4 v = xr[t];
  float s = v.x + v.y + v.z + v.w;
  float sq = v.x * v.x + v.y * v.y + v.z * v.z + v.w * v.w;
#pragma unroll
  for (int off = 32; off > 0; off >>= 1) {
    s += __shfl_down(s, off);
    sq += __shfl_down(sq, off);
  }
  __shared__ float ls[4], lq[4];
  int lane = t & 63, w = t >> 6;
  if (lane == 0) { ls[w] = s; lq[w] = sq; }
  __syncthreads();
  s = ls[0] + ls[1] + ls[2] + ls[3];
  sq = lq[0] + lq[1] + lq[2] + lq[3];
  float mean = s * (1.0f / D_);
  float var = sq * (1.0f / D_) - mean * mean;
  float rstd = rsqrtf(var + EPS_);
  float4 gv = ((const float4*)g)[t];
  float4 bv = ((const float4*)b)[t];
  us4 o, ob;
  o.x = f2bf((v.x - mean) * rstd * gv.x + bv.x);
  o.y = f2bf((v.y - mean) * rstd * gv.y + bv.y);
  o.z = f2bf((v.z - mean) * rstd * gv.z + bv.z);
  o.w = f2bf((v.w - mean) * rstd * gv.w + bv.w);
  ob.x = f2bf(v.x); ob.y = f2bf(v.y); ob.z = f2bf(v.z); ob.w = f2bf(v.w);
  ((us4*)(xn + (size_t)row * D_))[t] = o;
  ((us4*)(xb + (size_t)row * D_))[t] = ob;
}

// ---------------- conv pass 1: per-chunk local recurrence --------------------
__global__ __launch_bounds__(256) void conv_pass1(
    const unsigned short* __restrict__ xn, const float* __restrict__ ph_re,
    const float* __restrict__ ph_im, float2* __restrict__ rloc) {
  int d = blockIdx.x * 256 + threadIdx.x;
  int g = blockIdx.y, b = blockIdx.z;
  float re = ph_re[d], im = ph_im[d];
  float a = sqrtf(re * re + im * im);
  float sc = expf(-a) / a;
  float pr = re * sc, pi = im * sc;
  float rr = 0.f, ri = 0.f;
  const unsigned short* xp = xn + ((size_t)(b * L_ + g * CC)) * D_ + d;
#pragma unroll 8
  for (int l = 0; l < CC; ++l) {
    float xv = bf2f(xp[(size_t)l * D_]);
    float nr = pr * rr - pi * ri + xv;
    ri = pr * ri + pi * rr;
    rr = nr;
  }
  rloc[((size_t)(b * CG + g)) * D_ + d] = make_float2(rr, ri);
}

// ---------------- conv pass 2: scan over chunks (batch-8 prefetched) ---------
__global__ __launch_bounds__(256) void conv_pass2(
    const float* __restrict__ ph_re, const float* __restrict__ ph_im,
    const float2* __restrict__ rloc, float2* __restrict__ carry) {
  int idx = blockIdx.x * 256 + threadIdx.x;  // 0..B*D-1
  int b = idx >> 10, d = idx & (D_ - 1);
  float re = ph_re[d], im = ph_im[d];
  float a = sqrtf(re * re + im * im);
  float th = atan2f(im, re);
  float rho = expf(-a * (float)CC);
  float ang = th * (float)CC;
  float pcr = rho * cosf(ang), pci = rho * sinf(ang);
  float cr = 0.f, ci = 0.f;
  for (int g0 = 0; g0 < CG; g0 += 8) {
    float2 rl[8];
    float2 cw[8];
#pragma unroll
    for (int i = 0; i < 8; ++i)
      rl[i] = rloc[((size_t)(b * CG + g0 + i)) * D_ + d];
#pragma unroll
    for (int i = 0; i < 8; ++i) {
      cw[i] = make_float2(cr, ci);
      float nr = pcr * cr - pci * ci + rl[i].x;
      ci = pcr * ci + pci * cr + rl[i].y;
      cr = nr;
    }
#pragma unroll
    for (int i = 0; i < 8; ++i)
      carry[((size_t)(b * CG + g0 + i)) * D_ + d] = cw[i];
  }
}

// ---------------- conv pass 3: outputs -------------------------------------
__global__ __launch_bounds__(256) void conv_pass3(
    const unsigned short* __restrict__ xn,
    const float* __restrict__ ph_re, const float* __restrict__ ph_im,
    const float* __restrict__ phi_re, const float* __restrict__ phi_im,
    const float* __restrict__ lci_re, const float* __restrict__ lci_im,
    const float2* __restrict__ carry, unsigned short* __restrict__ cout) {
  int d = blockIdx.x * 256 + threadIdx.x;
  int g = blockIdx.y, b = blockIdx.z;
  float re = ph_re[d], im = ph_im[d];
  float a = sqrtf(re * re + im * im);
  float sc = expf(-a) / a;
  float pr = re * sc, pi = im * sc;
  float th = atan2f(im, re);
  int l0 = g * CC;
  float rho = expf(-a * (float)(l0 + 1));
  float ang = th * (float)(l0 + 1);
  float prr = rho * cosf(ang), pri = rho * sinf(ang);
  float fr = phi_re[d], fi = phi_im[d];
  float qr = lci_re[d], qi = lci_im[d];
  float2 cv = carry[((size_t)(b * CG + g)) * D_ + d];
  float rr = cv.x, ri = cv.y;
  const unsigned short* xp = xn + ((size_t)(b * L_ + l0)) * D_ + d;
  unsigned short* cp = cout + ((size_t)(b * L_ + l0)) * D_ + d;
#pragma unroll 4
  for (int l = 0; l < CC; ++l) {
    float xv = bf2f(xp[(size_t)l * D_]);
    float nr = pr * rr - pi * ri + xv;
    ri = pr * ri + pi * rr;
    rr = nr;
    float outv = fr * rr - fi * ri + qr * prr - qi * pri;  // Re(phi*r + lci*p)
    cp[(size_t)l * D_] = f2bf(outv);
    float pn = pr * prr - pi * pri;
    pri = pr * pri + pi * prr;
    prr = pn;
  }
}

// ------- LN2c: x3 = LN(x2 bf16) -> fp8 e4m3 (k-interleaved layout) ----------
__global__ __launch_bounds__(256) void ln2c_kernel(
    const unsigned short* __restrict__ x2, const float* __restrict__ g,
    const float* __restrict__ b, unsigned char* __restrict__ x3) {
  int row = blockIdx.x;
  int t = threadIdx.x;
  size_t base = (size_t)row * D_;
  us4 vb = ((const us4*)(x2 + base))[t];
  float4 v;
  v.x = bf2f(vb.x); v.y = bf2f(vb.y); v.z = bf2f(vb.z); v.w = bf2f(vb.w);
  float s = v.x + v.y + v.z + v.w;
  float sq = v.x * v.x + v.y * v.y + v.z * v.z + v.w * v.w;
#pragma unroll
  for (int off = 32; off > 0; off >>= 1) {
    s += __shfl_down(s, off);
    sq += __shfl_down(sq, off);
  }
  __shared__ float ls[4], lq[4];
  int lane = t & 63, w = t >> 6;
  if (lane == 0) { ls[w] = s; lq[w] = sq; }
  __syncthreads();
  s = ls[0] + ls[1] + ls[2] + ls[3];
  sq = lq[0] + lq[1] + lq[2] + lq[3];
  float mean = s * (1.0f / D_);
  float var = sq * (1.0f / D_) - mean * mean;
  float rstd = rsqrtf(var + EPS_);
  float4 gv = ((const float4*)g)[t];
  float4 bv = ((const float4*)b)[t];
  uchar4 o;
  o.x = f2fp8((v.x - mean) * rstd * gv.x + bv.x);
  o.y = f2fp8((v.y - mean) * rstd * gv.y + bv.y);
  o.z = f2fp8((v.z - mean) * rstd * gv.z + bv.z);
  o.w = f2fp8((v.w - mean) * rstd * gv.w + bv.w);
  int d = t * 4;
  size_t idx = base + (size_t)((d & ~63) + ph64(d & 63));
  *((uchar4*)(x3 + idx)) = o;
}

// ============================================================================
__device__ __forceinline__ void gld_lds16(const void* gp, void* lp) {
  __builtin_amdgcn_global_load_lds(
      (const __attribute__((address_space(1))) unsigned int*)gp,
      (__attribute__((address_space(3))) unsigned int*)lp, 16, 0, 0);
}

// ---------------- bf16 GEMM (single-phase K-tile): gemm1 only ---------------
// BM=256, BN=128, BK=64, 8 waves (4Mx2N), ring-3 144KiB, distance-2 staging.
// Per tile: [16 ds_read_b128][6 gld_lds stage(T+2)][lgkmcnt(0)+sched_barrier]
//           [setprio(1) 32 MFMA setprio(0)][vmcnt(6)][s_barrier]
// Epilogue: x2 = gate*silu(.)+x (f32 x), bf16 out.
__global__ __launch_bounds__(512) void gemm_bt_gate(
    const unsigned short* __restrict__ A, const unsigned short* __restrict__ Bt,
    const float* __restrict__ bias,
    const unsigned short* __restrict__ gate, const float* __restrict__ xresf,
    unsigned short* __restrict__ Cv, int NB, int GROUP, int N, int K) {
  __shared__ unsigned short As[3][256 * 64];
  __shared__ unsigned short Bs[3][128 * 64];

  int nwg = gridDim.x;
  int xcd = blockIdx.x & 7;
  int lo = blockIdx.x >> 3;
  int q = nwg >> 3;
  int gsz = GROUP * NB;
  int g_ = lo / gsz, r_ = lo % gsz;
  int n_ = r_ / GROUP, ml = r_ - n_ * GROUP;
  int Mx = q / NB;
  int bm0 = (xcd * Mx + g_ * GROUP + ml) * 256;
  int bn0 = n_ * 128;

  int t = threadIdx.x;
  int lane = t & 63, w = t >> 6;
  int wr = w >> 1, wc = w & 1;
  int frr = lane & 15, cl = lane >> 4;
  int fx = frr & 7;
  int rA0 = wr * 64 + frr;
  int rB0 = wc * 64 + frr;
  int ko0 = (cl ^ fx) * 8;
  int ko1 = ((4 + cl) ^ fx) * 8;

  int nt = K >> 6;

  int tr = t >> 3;
  int jx = (t & 7) ^ (tr & 7);
  const unsigned short* pA = A + (size_t)(bm0 + tr) * K + jx * 8;
  const unsigned short* pB = Bt + (size_t)(bn0 + tr) * K + jx * 8;

  auto stA = [&](int kt2, int slot, int c) {
    gld_lds16(pA + (size_t)kt2 * 64 + (size_t)c * 64 * K, &As[slot][c * 4096 + t * 8]);
  };
  auto stB = [&](int kt2, int slot, int c) {
    gld_lds16(pB + (size_t)kt2 * 64 + (size_t)c * 64 * K, &Bs[slot][c * 4096 + t * 8]);
  };

  f32x4 acc[4][4] = {};

  stA(0, 0, 0); stA(0, 0, 1); stA(0, 0, 2); stA(0, 0, 3); stB(0, 0, 0); stB(0, 0, 1);
  stA(1, 1, 0); stA(1, 1, 1); stA(1, 1, 2); stA(1, 1, 3); stB(1, 1, 0); stB(1, 1, 1);
  asm volatile("s_waitcnt vmcnt(6)" ::: "memory");
  __builtin_amdgcn_s_barrier();

  int s = 0;
  for (int kt = 0; kt < nt; ++kt) {
    const unsigned short* as = As[s];
    const unsigned short* bs = Bs[s];
    int s2 = s + 2; if (s2 >= 3) s2 -= 3;
    bool p2 = kt + 2 < nt;

    bf16x8 a0[4], b0[4], a1[4], b1[4];
#pragma unroll
    for (int m = 0; m < 4; ++m) a0[m] = *(const bf16x8*)&as[(rA0 + m * 16) * 64 + ko0];
#pragma unroll
    for (int n = 0; n < 4; ++n) b0[n] = *(const bf16x8*)&bs[(rB0 + n * 16) * 64 + ko0];
#pragma unroll
    for (int m = 0; m < 4; ++m) a1[m] = *(const bf16x8*)&as[(rA0 + m * 16) * 64 + ko1];
#pragma unroll
    for (int n = 0; n < 4; ++n) b1[n] = *(const bf16x8*)&bs[(rB0 + n * 16) * 64 + ko1];
    if (p2) {
      stA(kt + 2, s2, 0); stA(kt + 2, s2, 1); stA(kt + 2, s2, 2); stA(kt + 2, s2, 3);
      stB(kt + 2, s2, 0); stB(kt + 2, s2, 1);
    }

    asm volatile("s_waitcnt lgkmcnt(0)" ::: "memory");
    __builtin_amdgcn_sched_barrier(0);
    __builtin_amdgcn_s_setprio(1);
#pragma unroll
    for (int m = 0; m < 4; ++m)
#pragma unroll
      for (int n = 0; n < 4; ++n)
        acc[m][n] = __builtin_amdgcn_mfma_f32_16x16x32_bf16(a0[m], b0[n], acc[m][n], 0, 0, 0);
#pragma unroll
    for (int m = 0; m < 4; ++m)
#pragma unroll
      for (int n = 0; n < 4; ++n)
        acc[m][n] = __builtin_amdgcn_mfma_f32_16x16x32_bf16(a1[m], b1[n], acc[m][n], 0, 0, 0);
    __builtin_amdgcn_s_setprio(0);

    if (p2) { asm volatile("s_waitcnt vmcnt(6)" ::: "memory"); }
    else    { asm volatile("s_waitcnt vmcnt(0)" ::: "memory"); }
    __builtin_amdgcn_s_barrier();
    s += 1; if (s == 3) s = 0;
  }

#pragma unroll
  for (int m = 0; m < 4; ++m) {
#pragma unroll
    for (int n = 0; n < 4; ++n) {
#pragma unroll
      for (int r = 0; r < 4; ++r) {
        int row = bm0 + wr * 64 + m * 16 + cl * 4 + r;
        int col = bn0 + wc * 64 + n * 16 + frr;
        size_t o = (size_t)row * N + col;
        float v = acc[m][n][r] + bias[col];
        v = v / (1.0f + __expf(-v));
        v = bf2f(gate[o]) * v + xresf[o];
        Cv[o] = f2bf(v);
      }
    }
  }
}

// ------- fp8 GEMM (k-interleaved, b128 reads, single-phase K-tile) ----------
// BM=256, BN=128, BK=64, 8 waves (4Mx2N), ring-3 = 72 KiB -> 2 blocks/CU.
// Global fp8 layout is k-interleaved (ph64): 16B chunk c = k-blocks {c, c+4},
// so ONE ds_read_b128 per (m) yields ks=0 (.x) and ks=1 (.y) fragments.
// 8 b128/tile (vs 16 b64) with the bf16-proven conflict-free pattern.
// Per tile: [8 ds_read_b128][3 gld_lds stage(T+2)][lgkmcnt(0)+sched_barrier]
//           [setprio(1) 32 MFMA setprio(0)][vmcnt(3)][s_barrier]
// OUT: 0=f32(+bf16 res), 1=fp8 (k-interleaved store for next gemm).
template <int SILU, int RESBF, int OUT_FP8>
__global__ __launch_bounds__(512, 4) void gemm_f8(
    const unsigned char* __restrict__ A, const unsigned char* __restrict__ Bt,
    const float* __restrict__ bias, const unsigned short* __restrict__ resb,
    float oscale, void* __restrict__ Cv, int NB, int GROUP, int N, int K) {
  __shared__ unsigned char As[3][256 * 64];  // 3 x 16 KiB
  __shared__ unsigned char Bs[3][128 * 64];  // 3 x 8 KiB

  int nwg = gridDim.x;
  int xcd = blockIdx.x & 7;
  int lo = blockIdx.x >> 3;
  int q = nwg >> 3;
  int gsz = GROUP * NB;
  int g_ = lo / gsz, r_ = lo % gsz;
  int n_ = r_ / GROUP, ml = r_ - n_ * GROUP;
  int Mx = q / NB;
  int bm0 = (xcd * Mx + g_ * GROUP + ml) * 256;
  int bn0 = n_ * 128;

  int t = threadIdx.x;
  int lane = t & 63, w = t >> 6;
  int wr = w >> 1, wc = w & 1;          // 4M x 2N
  int frr = lane & 15, cl = lane >> 4;  // row, k-chunk (0..3)
  int sw = (frr >> 1) & 3;              // swizzle key
  int rA0 = wr * 64 + frr;
  int rB0 = wc * 64 + frr;
  int ko = (cl ^ sw) * 16;              // b128 chunk (holds blocks {cl, cl+4})

  int nt = K >> 6;  // K-tiles of 64 fp8

  // staging: 128 rows/call; thread t -> row t>>2, LDS chunk t&3, global chunk jc
  int tr = t >> 2;                      // 0..127
  int jc = (t & 3) ^ ((tr >> 1) & 3);
  const unsigned char* pA = A + (size_t)(bm0 + tr) * K + jc * 16;
  const unsigned char* pB = Bt + (size_t)(bn0 + tr) * K + jc * 16;

  auto stA = [&](int kt2, int slot, int c) {  // c=0: rows 0-127, c=1: 128-255
    gld_lds16(pA + (size_t)kt2 * 64 + (size_t)c * 128 * K, &As[slot][c * 8192 + t * 16]);
  };
  auto stB = [&](int kt2, int slot) {
    gld_lds16(pB + (size_t)kt2 * 64, &Bs[slot][t * 16]);
  };

  f32x4 acc[4][4] = {};

  // prologue: stage T0 (3), T1 (3); vmcnt(3) -> T0 landed
  stA(0, 0, 0); stA(0, 0, 1); stB(0, 0);
  stA(1, 1, 0); stA(1, 1, 1); stB(1, 1);
  asm volatile("s_waitcnt vmcnt(3)" ::: "memory");
  __builtin_amdgcn_s_barrier();

  int s = 0;
  for (int kt = 0; kt < nt; ++kt) {
    const unsigned char* as = As[s];
    const unsigned char* bs = Bs[s];
    int s2 = s + 2; if (s2 >= 3) s2 -= 3;
    bool p2 = kt + 2 < nt;

    l2 av[4], bv[4];
#pragma unroll
    for (int m = 0; m < 4; ++m) av[m] = *(const l2*)&as[(rA0 + m * 16) * 64 + ko];
#pragma unroll
    for (int n = 0; n < 4; ++n) bv[n] = *(const l2*)&bs[(rB0 + n * 16) * 64 + ko];
    if (p2) { stA(kt + 2, s2, 0); stA(kt + 2, s2, 1); stB(kt + 2, s2); }

    asm volatile("s_waitcnt lgkmcnt(0)" ::: "memory");
    __builtin_amdgcn_sched_barrier(0);
    __builtin_amdgcn_s_setprio(1);
#pragma unroll
    for (int m = 0; m < 4; ++m)
#pragma unroll
      for (int n = 0; n < 4; ++n)
        acc[m][n] = __builtin_amdgcn_mfma_f32_16x16x32_fp8_fp8(av[m].x, bv[n].x, acc[m][n], 0, 0, 0);
#pragma unroll
    for (int m = 0; m < 4; ++m)
#pragma unroll
      for (int n = 0; n < 4; ++n)
        acc[m][n] = __builtin_amdgcn_mfma_f32_16x16x32_fp8_fp8(av[m].y, bv[n].y, acc[m][n], 0, 0, 0);
    __builtin_amdgcn_s_setprio(0);

    if (p2) { asm volatile("s_waitcnt vmcnt(3)" ::: "memory"); }
    else    { asm volatile("s_waitcnt vmcnt(0)" ::: "memory"); }
    __builtin_amdgcn_s_barrier();
    s += 1; if (s == 3) s = 0;
  }

  // epilogue (16x16 C layout: col=lane&15, row=(lane>>4)*4+reg)
#pragma unroll
  for (int m = 0; m < 4; ++m) {
#pragma unroll
    for (int n = 0; n < 4; ++n) {
#pragma unroll
      for (int r = 0; r < 4; ++r) {
        int row = bm0 + wr * 64 + m * 16 + cl * 4 + r;
        int col = bn0 + wc * 64 + n * 16 + frr;
        size_t o = (size_t)row * N + col;
        float v = acc[m][n][r] * oscale + bias[col];
        if (SILU) v = v / (1.0f + __expf(-v));
        if (RESBF) v += bf2f(resb[o]);
        if (OUT_FP8) {
          int e = n * 16 + frr;  // col & 63 (bn0%128==0, wc*64%64==0)
          size_t op = (size_t)row * N + bn0 + wc * 64 + ph64(e);
          ((unsigned char*)Cv)[op] = f2fp8(v);
        } else {
          ((float*)Cv)[o] = v;
        }
      }
    }
  }
}

// ---------------------------------------------------------------------------
extern "C" void kernel_launch(void* const* d_in, const int* in_sizes, int n_in,
                              void* d_out, int out_size, void* d_ws, size_t ws_size,
                              hipStream_t stream) {
  const float* x      = (const float*)d_in[0];
  const float* ln_g   = (const float*)d_in[1];
  const float* ln_b   = (const float*)d_in[2];
  const float* fc_w   = (const float*)d_in[3];
  const float* fc_b   = (const float*)d_in[4];
  const float* w1     = (const float*)d_in[5];
  const float* b1     = (const float*)d_in[6];
  const float* w2     = (const float*)d_in[7];
  const float* b2     = (const float*)d_in[8];
  const float* ph_re  = (const float*)d_in[9];
  const float* ph_im  = (const float*)d_in[10];
  const float* phi_re = (const float*)d_in[11];
  const float* phi_im = (const float*)d_in[12];
  const float* lci_re = (const float*)d_in[13];
  const float* lci_im = (const float*)d_in[14];
  float* out = (float*)d_out;

  char* ws = (char*)d_ws;
  const size_t SZ_BF = (size_t)ROWS * D_ * 2;   // 32 MiB
  const size_t SZ_F8 = (size_t)ROWS * D_;       // 16 MiB
  unsigned short* xn_x2 = (unsigned short*)(ws);               // xn; then x2 bf16
  unsigned short* cbuf  = (unsigned short*)(ws + SZ_BF);       // conv out bf16
  unsigned short* xb    = (unsigned short*)(ws + 2 * SZ_BF);   // x bf16 (gemm1 A)
  unsigned char*  x3f8  = (unsigned char*)(ws + 3 * SZ_BF);    // x3 fp8 (16 MiB)
  unsigned char*  h1f8  = (unsigned char*)(ws + 3 * SZ_BF + SZ_F8);  // h1 fp8 (32 MiB)
  char* wp = ws + 3 * SZ_BF + SZ_F8 + (size_t)ROWS * FF_;
  unsigned short* fc_wt = (unsigned short*)(wp);                       // 2 MiB
  unsigned char*  w1t8  = (unsigned char*)(wp + (size_t)D_ * D_ * 2);  // 2 MiB
  unsigned char*  w2t8  = (unsigned char*)(wp + (size_t)D_ * D_ * 2 + (size_t)D_ * FF_);
  float2* rloc  = (float2*)(wp + (size_t)D_ * D_ * 2 + 2 * (size_t)D_ * FF_);
  float2* carry = rloc + (size_t)B_ * CG * D_;

  // weight prep
  transpose_cast<<<dim3(D_ / 32, D_ / 32), 256, 0, stream>>>(fc_w, fc_wt, D_, D_);
  transpose_cast_fp8<<<dim3(FF_ / 32, D_ / 32), 256, 0, stream>>>(w1, w1t8, D_, FF_, 32.0f);
  transpose_cast_fp8<<<dim3(D_ / 32, FF_ / 32), 256, 0, stream>>>(w2, w2t8, FF_, D_, 32.0f);

  // LN1: xn bf16 (conv input) + xb bf16 (gemm1 A)
  ln1_kernel<<<ROWS, 256, 0, stream>>>(x, ln_g, ln_b, xn_x2, xb);

  // conv (chunked scan)
  conv_pass1<<<dim3(D_ / 256, CG, B_), 256, 0, stream>>>(xn_x2, ph_re, ph_im, rloc);
  conv_pass2<<<dim3((B_ * D_) / 256), 256, 0, stream>>>(ph_re, ph_im, rloc, carry);
  conv_pass3<<<dim3(D_ / 256, CG, B_), 256, 0, stream>>>(xn_x2, ph_re, ph_im, phi_re, phi_im,
                                                         lci_re, lci_im, carry, cbuf);

  // x2 = c * silu(x @ fc_w + fc_b) + x   (bf16 gemm, bf16 out -> xn region)
  gemm_bt_gate<<<(ROWS / 256) * (D_ / 128), 512, 0, stream>>>(
      xb, fc_wt, fc_b, cbuf, x, xn_x2, D_ / 128, 4, D_, D_);

  // x3 = LN(x2) -> fp8 (k-interleaved)
  ln2c_kernel<<<ROWS, 256, 0, stream>>>(xn_x2, ln_g, ln_b, x3f8);

  // h1 = silu(x3 @ (32*w1)/32 + b1) -> fp8 (k-interleaved)
  gemm_f8<1, 0, 1><<<(ROWS / 256) * (FF_ / 128), 512, 0, stream>>>(
      x3f8, w1t8, b1, nullptr, 1.0f / 32.0f, h1f8, FF_ / 128, 4, FF_, D_);

  // out = x2 + h1 @ (32*w2)/32 + b2   (f32 out; residual read bf16)
  gemm_f8<0, 1, 0><<<(ROWS / 256) * (D_ / 128), 512, 0, stream>>>(
      h1f8, w2t8, b2, xn_x2, 1.0f / 32.0f, out, D_ / 128, 2, D_, FF_);
}

// Round 16
// 247.886 us; speedup vs baseline: 1.0873x; 1.0472x over previous
//
#include <hip/hip_runtime.h>
#include <hip/hip_bf16.h>
#include <hip/hip_fp8.h>
#include <cstdint>
#include <cstddef>

#define B_ 4
#define L_ 4096
#define D_ 1024
#define FF_ 2048
#define ROWS (B_ * L_)   // 16384
#define EPS_ 1e-5f
#define CG 64            // conv chunks
#define CC 64            // conv chunk length (L_/CG)

typedef __attribute__((ext_vector_type(8))) __bf16 bf16x8;
typedef __attribute__((ext_vector_type(4))) float f32x4;
typedef __attribute__((ext_vector_type(4))) unsigned short us4;
typedef __attribute__((ext_vector_type(2))) long l2;

__device__ __forceinline__ float bf2f(unsigned short u) {
  union { unsigned int i; float f; } v; v.i = ((unsigned int)u) << 16; return v.f;
}
__device__ __forceinline__ unsigned short f2bf(float f) {
  union { float f; unsigned int i; } v; v.f = f;
  unsigned int r = v.i + 0x7fffu + ((v.i >> 16) & 1u);
  return (unsigned short)(r >> 16);
}
__device__ __forceinline__ unsigned char f2fp8(float f) {
  __hip_fp8_e4m3 q(f);
  return *reinterpret_cast<unsigned char*>(&q);
}
// k-interleave permutation within 64-byte groups: phys block order {0,4,1,5,2,6,3,7}
__device__ __forceinline__ int ph64(int e) {  // e in [0,64)
  return (((e >> 3) & 3) << 4) | (((e >> 5) & 1) << 3) | (e & 7);
}

// ---------------- weight transpose + cast: in [K,N] f32 -> out [N,K] bf16 ----
__global__ __launch_bounds__(256) void transpose_cast(
    const float* __restrict__ in, unsigned short* __restrict__ out, int K, int N) {
  __shared__ float tb[32][33];
  int n0 = blockIdx.x * 32, k0 = blockIdx.y * 32;
  int tx = threadIdx.x & 31, ty = threadIdx.x >> 5;  // 32 x 8
#pragma unroll
  for (int i = 0; i < 4; ++i) {
    int k = ty + i * 8;
    tb[k][tx] = in[(size_t)(k0 + k) * N + n0 + tx];
  }
  __syncthreads();
#pragma unroll
  for (int i = 0; i < 4; ++i) {
    int n = ty + i * 8;
    out[(size_t)(n0 + n) * K + k0 + tx] = f2bf(tb[tx][n]);
  }
}

// -------- weight transpose + cast fp8 (k-interleaved): [K,N] -> [N,K] --------
__global__ __launch_bounds__(256) void transpose_cast_fp8(
    const float* __restrict__ in, unsigned char* __restrict__ out, int K, int N,
    float scale) {
  __shared__ float tb[32][33];
  int n0 = blockIdx.x * 32, k0 = blockIdx.y * 32;
  int tx = threadIdx.x & 31, ty = threadIdx.x >> 5;
#pragma unroll
  for (int i = 0; i < 4; ++i) {
    int k = ty + i * 8;
    tb[k][tx] = in[(size_t)(k0 + k) * N + n0 + tx];
  }
  __syncthreads();
#pragma unroll
  for (int i = 0; i < 4; ++i) {
    int n = ty + i * 8;
    int k = k0 + tx;
    size_t idx = (size_t)(n0 + n) * K + (k & ~63) + ph64(k & 63);
    out[idx] = f2fp8(tb[tx][n] * scale);
  }
}

// ---------------- LN1: x -> xn bf16 (LayerNorm), xb bf16 (plain cast) --------
__global__ __launch_bounds__(256) void ln1_kernel(
    const float* __restrict__ x, const float* __restrict__ g, const float* __restrict__ b,
    unsigned short* __restrict__ xn, unsigned short* __restrict__ xb) {
  int row = blockIdx.x;
  int t = threadIdx.x;
  const float4* xr = (const float4*)(x + (size_t)row * D_);
  float4 v = xr[t];
  float s = v.x + v.y + v.z + v.w;
  float sq = v.x * v.x + v.y * v.y + v.z * v.z + v.w * v.w;
#pragma unroll
  for (int off = 32; off > 0; off >>= 1) {
    s += __shfl_down(s, off);
    sq += __shfl_down(sq, off);
  }
  __shared__ float ls[4], lq[4];
  int lane = t & 63, w = t >> 6;
  if (lane == 0) { ls[w] = s; lq[w] = sq; }
  __syncthreads();
  s = ls[0] + ls[1] + ls[2] + ls[3];
  sq = lq[0] + lq[1] + lq[2] + lq[3];
  float mean = s * (1.0f / D_);
  float var = sq * (1.0f / D_) - mean * mean;
  float rstd = rsqrtf(var + EPS_);
  float4 gv = ((const float4*)g)[t];
  float4 bv = ((const float4*)b)[t];
  us4 o, ob;
  o.x = f2bf((v.x - mean) * rstd * gv.x + bv.x);
  o.y = f2bf((v.y - mean) * rstd * gv.y + bv.y);
  o.z = f2bf((v.z - mean) * rstd * gv.z + bv.z);
  o.w = f2bf((v.w - mean) * rstd * gv.w + bv.w);
  ob.x = f2bf(v.x); ob.y = f2bf(v.y); ob.z = f2bf(v.z); ob.w = f2bf(v.w);
  ((us4*)(xn + (size_t)row * D_))[t] = o;
  ((us4*)(xb + (size_t)row * D_))[t] = ob;
}

// ---------------- conv pass 1: per-chunk local recurrence --------------------
__global__ __launch_bounds__(256) void conv_pass1(
    const unsigned short* __restrict__ xn, const float* __restrict__ ph_re,
    const float* __restrict__ ph_im, float2* __restrict__ rloc) {
  int d = blockIdx.x * 256 + threadIdx.x;
  int g = blockIdx.y, b = blockIdx.z;
  float re = ph_re[d], im = ph_im[d];
  float a = sqrtf(re * re + im * im);
  float sc = expf(-a) / a;
  float pr = re * sc, pi = im * sc;
  float rr = 0.f, ri = 0.f;
  const unsigned short* xp = xn + ((size_t)(b * L_ + g * CC)) * D_ + d;
#pragma unroll 8
  for (int l = 0; l < CC; ++l) {
    float xv = bf2f(xp[(size_t)l * D_]);
    float nr = pr * rr - pi * ri + xv;
    ri = pr * ri + pi * rr;
    rr = nr;
  }
  rloc[((size_t)(b * CG + g)) * D_ + d] = make_float2(rr, ri);
}

// ---------------- conv pass 2: scan over chunks (batch-8 prefetched) ---------
__global__ __launch_bounds__(256) void conv_pass2(
    const float* __restrict__ ph_re, const float* __restrict__ ph_im,
    const float2* __restrict__ rloc, float2* __restrict__ carry) {
  int idx = blockIdx.x * 256 + threadIdx.x;  // 0..B*D-1
  int b = idx >> 10, d = idx & (D_ - 1);
  float re = ph_re[d], im = ph_im[d];
  float a = sqrtf(re * re + im * im);
  float th = atan2f(im, re);
  float rho = expf(-a * (float)CC);
  float ang = th * (float)CC;
  float pcr = rho * cosf(ang), pci = rho * sinf(ang);
  float cr = 0.f, ci = 0.f;
  for (int g0 = 0; g0 < CG; g0 += 8) {
    float2 rl[8];
    float2 cw[8];
#pragma unroll
    for (int i = 0; i < 8; ++i)
      rl[i] = rloc[((size_t)(b * CG + g0 + i)) * D_ + d];
#pragma unroll
    for (int i = 0; i < 8; ++i) {
      cw[i] = make_float2(cr, ci);
      float nr = pcr * cr - pci * ci + rl[i].x;
      ci = pcr * ci + pci * cr + rl[i].y;
      cr = nr;
    }
#pragma unroll
    for (int i = 0; i < 8; ++i)
      carry[((size_t)(b * CG + g0 + i)) * D_ + d] = cw[i];
  }
}

// ---------------- conv pass 3: outputs -------------------------------------
__global__ __launch_bounds__(256) void conv_pass3(
    const unsigned short* __restrict__ xn,
    const float* __restrict__ ph_re, const float* __restrict__ ph_im,
    const float* __restrict__ phi_re, const float* __restrict__ phi_im,
    const float* __restrict__ lci_re, const float* __restrict__ lci_im,
    const float2* __restrict__ carry, unsigned short* __restrict__ cout) {
  int d = blockIdx.x * 256 + threadIdx.x;
  int g = blockIdx.y, b = blockIdx.z;
  float re = ph_re[d], im = ph_im[d];
  float a = sqrtf(re * re + im * im);
  float sc = expf(-a) / a;
  float pr = re * sc, pi = im * sc;
  float th = atan2f(im, re);
  int l0 = g * CC;
  float rho = expf(-a * (float)(l0 + 1));
  float ang = th * (float)(l0 + 1);
  float prr = rho * cosf(ang), pri = rho * sinf(ang);
  float fr = phi_re[d], fi = phi_im[d];
  float qr = lci_re[d], qi = lci_im[d];
  float2 cv = carry[((size_t)(b * CG + g)) * D_ + d];
  float rr = cv.x, ri = cv.y;
  const unsigned short* xp = xn + ((size_t)(b * L_ + l0)) * D_ + d;
  unsigned short* cp = cout + ((size_t)(b * L_ + l0)) * D_ + d;
#pragma unroll 4
  for (int l = 0; l < CC; ++l) {
    float xv = bf2f(xp[(size_t)l * D_]);
    float nr = pr * rr - pi * ri + xv;
    ri = pr * ri + pi * rr;
    rr = nr;
    float outv = fr * rr - fi * ri + qr * prr - qi * pri;  // Re(phi*r + lci*p)
    cp[(size_t)l * D_] = f2bf(outv);
    float pn = pr * prr - pi * pri;
    pri = pr * pri + pi * prr;
    prr = pn;
  }
}

// ------- LN2c: x3 = LN(x2 bf16) -> fp8 e4m3 (k-interleaved layout) ----------
__global__ __launch_bounds__(256) void ln2c_kernel(
    const unsigned short* __restrict__ x2, const float* __restrict__ g,
    const float* __restrict__ b, unsigned char* __restrict__ x3) {
  int row = blockIdx.x;
  int t = threadIdx.x;
  size_t base = (size_t)row * D_;
  us4 vb = ((const us4*)(x2 + base))[t];
  float4 v;
  v.x = bf2f(vb.x); v.y = bf2f(vb.y); v.z = bf2f(vb.z); v.w = bf2f(vb.w);
  float s = v.x + v.y + v.z + v.w;
  float sq = v.x * v.x + v.y * v.y + v.z * v.z + v.w * v.w;
#pragma unroll
  for (int off = 32; off > 0; off >>= 1) {
    s += __shfl_down(s, off);
    sq += __shfl_down(sq, off);
  }
  __shared__ float ls[4], lq[4];
  int lane = t & 63, w = t >> 6;
  if (lane == 0) { ls[w] = s; lq[w] = sq; }
  __syncthreads();
  s = ls[0] + ls[1] + ls[2] + ls[3];
  sq = lq[0] + lq[1] + lq[2] + lq[3];
  float mean = s * (1.0f / D_);
  float var = sq * (1.0f / D_) - mean * mean;
  float rstd = rsqrtf(var + EPS_);
  float4 gv = ((const float4*)g)[t];
  float4 bv = ((const float4*)b)[t];
  uchar4 o;
  o.x = f2fp8((v.x - mean) * rstd * gv.x + bv.x);
  o.y = f2fp8((v.y - mean) * rstd * gv.y + bv.y);
  o.z = f2fp8((v.z - mean) * rstd * gv.z + bv.z);
  o.w = f2fp8((v.w - mean) * rstd * gv.w + bv.w);
  int d = t * 4;
  size_t idx = base + (size_t)((d & ~63) + ph64(d & 63));
  *((uchar4*)(x3 + idx)) = o;
}

// ============================================================================
__device__ __forceinline__ void gld_lds16(const void* gp, void* lp) {
  __builtin_amdgcn_global_load_lds(
      (const __attribute__((address_space(1))) unsigned int*)gp,
      (__attribute__((address_space(3))) unsigned int*)lp, 16, 0, 0);
}

// ------- bf16 GEMM, f8-style structure: BK=32, 2 blocks/CU (gemm1) ----------
// BM=256, BN=128, BK=32. 512 thr = 8 waves (4Mx2N), wave-tile 64x64.
// LDS ring-3 of (A 16K + B 8K) = 72 KiB -> 2 blocks/CU. Per K-tile:
//   [8 ds_read_b128][3 gld_lds stage(T+2)][lgkmcnt(0)+sched_barrier]
//   [setprio(1) 16 MFMA setprio(0)][vmcnt(3)][s_barrier]
// Ledger: outstanding at wait = S(T+1) 3 + S(T+2) 3 -> vmcnt(3) = S(T+1)
// landed (issued a full tile earlier). Swizzle: R7-proven BK=32 pattern
// (16B chunk ^= (row>>1)&3, pre-swizzled source; measured 0 conflicts).
// Epilogue: x2 = gate*silu(.) + xb (bf16 residual), bf16 out.
__global__ __launch_bounds__(512, 4) void gemm_bt_gate(
    const unsigned short* __restrict__ A, const unsigned short* __restrict__ Bt,
    const float* __restrict__ bias,
    const unsigned short* __restrict__ gate, const unsigned short* __restrict__ xresb,
    unsigned short* __restrict__ Cv, int NB, int GROUP, int N, int K) {
  __shared__ unsigned short As[3][256 * 32];  // 3 x 16 KiB
  __shared__ unsigned short Bs[3][128 * 32];  // 3 x 8 KiB

  int nwg = gridDim.x;
  int xcd = blockIdx.x & 7;
  int lo = blockIdx.x >> 3;
  int q = nwg >> 3;
  int gsz = GROUP * NB;
  int g_ = lo / gsz, r_ = lo % gsz;
  int n_ = r_ / GROUP, ml = r_ - n_ * GROUP;
  int Mx = q / NB;
  int bm0 = (xcd * Mx + g_ * GROUP + ml) * 256;
  int bn0 = n_ * 128;

  int t = threadIdx.x;
  int lane = t & 63, w = t >> 6;
  int wr = w >> 1, wc = w & 1;          // 4M x 2N
  int frr = lane & 15, cl = lane >> 4;  // row, k-chunk (0..3)
  int sw = (frr >> 1) & 3;
  int rA0 = wr * 64 + frr;
  int rB0 = wc * 64 + frr;
  int ko = (cl ^ sw) * 8;               // 16B chunk offset in shorts

  int nt = K >> 5;  // K-tiles of 32

  // staging: 128 rows/call; thread t -> row t>>2, global 16B chunk jc
  int tr = t >> 2;                      // 0..127
  int jc = (t & 3) ^ ((tr >> 1) & 3);
  const unsigned short* pA = A + (size_t)(bm0 + tr) * K + jc * 8;
  const unsigned short* pB = Bt + (size_t)(bn0 + tr) * K + jc * 8;

  auto stA = [&](int kt2, int slot, int c) {  // c=0: rows 0-127, c=1: 128-255
    gld_lds16(pA + (size_t)kt2 * 32 + (size_t)c * 128 * K, &As[slot][c * 4096 + t * 8]);
  };
  auto stB = [&](int kt2, int slot) {
    gld_lds16(pB + (size_t)kt2 * 32, &Bs[slot][t * 8]);
  };

  f32x4 acc[4][4] = {};

  // prologue: stage T0 (3), T1 (3); vmcnt(3) -> T0 landed
  stA(0, 0, 0); stA(0, 0, 1); stB(0, 0);
  stA(1, 1, 0); stA(1, 1, 1); stB(1, 1);
  asm volatile("s_waitcnt vmcnt(3)" ::: "memory");
  __builtin_amdgcn_s_barrier();

  int s = 0;
  for (int kt = 0; kt < nt; ++kt) {
    const unsigned short* as = As[s];
    const unsigned short* bs = Bs[s];
    int s2 = s + 2; if (s2 >= 3) s2 -= 3;
    bool p2 = kt + 2 < nt;

    bf16x8 av[4], bv[4];
#pragma unroll
    for (int m = 0; m < 4; ++m) av[m] = *(const bf16x8*)&as[(rA0 + m * 16) * 32 + ko];
#pragma unroll
    for (int n = 0; n < 4; ++n) bv[n] = *(const bf16x8*)&bs[(rB0 + n * 16) * 32 + ko];
    if (p2) { stA(kt + 2, s2, 0); stA(kt + 2, s2, 1); stB(kt + 2, s2); }

    asm volatile("s_waitcnt lgkmcnt(0)" ::: "memory");
    __builtin_amdgcn_sched_barrier(0);
    __builtin_amdgcn_s_setprio(1);
#pragma unroll
    for (int m = 0; m < 4; ++m)
#pragma unroll
      for (int n = 0; n < 4; ++n)
        acc[m][n] = __builtin_amdgcn_mfma_f32_16x16x32_bf16(av[m], bv[n], acc[m][n], 0, 0, 0);
    __builtin_amdgcn_s_setprio(0);

    if (p2) { asm volatile("s_waitcnt vmcnt(3)" ::: "memory"); }
    else    { asm volatile("s_waitcnt vmcnt(0)" ::: "memory"); }
    __builtin_amdgcn_s_barrier();
    s += 1; if (s == 3) s = 0;
  }

#pragma unroll
  for (int m = 0; m < 4; ++m) {
#pragma unroll
    for (int n = 0; n < 4; ++n) {
#pragma unroll
      for (int r = 0; r < 4; ++r) {
        int row = bm0 + wr * 64 + m * 16 + cl * 4 + r;
        int col = bn0 + wc * 64 + n * 16 + frr;
        size_t o = (size_t)row * N + col;
        float v = acc[m][n][r] + bias[col];
        v = v / (1.0f + __expf(-v));
        v = bf2f(gate[o]) * v + bf2f(xresb[o]);
        Cv[o] = f2bf(v);
      }
    }
  }
}

// ------- fp8 GEMM (k-interleaved, b128 reads, single-phase K-tile) ----------
// UNCHANGED from R15 (proven 67 us, 0 conflicts).
template <int SILU, int RESBF, int OUT_FP8>
__global__ __launch_bounds__(512, 4) void gemm_f8(
    const unsigned char* __restrict__ A, const unsigned char* __restrict__ Bt,
    const float* __restrict__ bias, const unsigned short* __restrict__ resb,
    float oscale, void* __restrict__ Cv, int NB, int GROUP, int N, int K) {
  __shared__ unsigned char As[3][256 * 64];  // 3 x 16 KiB
  __shared__ unsigned char Bs[3][128 * 64];  // 3 x 8 KiB

  int nwg = gridDim.x;
  int xcd = blockIdx.x & 7;
  int lo = blockIdx.x >> 3;
  int q = nwg >> 3;
  int gsz = GROUP * NB;
  int g_ = lo / gsz, r_ = lo % gsz;
  int n_ = r_ / GROUP, ml = r_ - n_ * GROUP;
  int Mx = q / NB;
  int bm0 = (xcd * Mx + g_ * GROUP + ml) * 256;
  int bn0 = n_ * 128;

  int t = threadIdx.x;
  int lane = t & 63, w = t >> 6;
  int wr = w >> 1, wc = w & 1;          // 4M x 2N
  int frr = lane & 15, cl = lane >> 4;  // row, k-chunk (0..3)
  int sw = (frr >> 1) & 3;              // swizzle key
  int rA0 = wr * 64 + frr;
  int rB0 = wc * 64 + frr;
  int ko = (cl ^ sw) * 16;              // b128 chunk (holds blocks {cl, cl+4})

  int nt = K >> 6;  // K-tiles of 64 fp8

  int tr = t >> 2;                      // 0..127
  int jc = (t & 3) ^ ((tr >> 1) & 3);
  const unsigned char* pA = A + (size_t)(bm0 + tr) * K + jc * 16;
  const unsigned char* pB = Bt + (size_t)(bn0 + tr) * K + jc * 16;

  auto stA = [&](int kt2, int slot, int c) {  // c=0: rows 0-127, c=1: 128-255
    gld_lds16(pA + (size_t)kt2 * 64 + (size_t)c * 128 * K, &As[slot][c * 8192 + t * 16]);
  };
  auto stB = [&](int kt2, int slot) {
    gld_lds16(pB + (size_t)kt2 * 64, &Bs[slot][t * 16]);
  };

  f32x4 acc[4][4] = {};

  stA(0, 0, 0); stA(0, 0, 1); stB(0, 0);
  stA(1, 1, 0); stA(1, 1, 1); stB(1, 1);
  asm volatile("s_waitcnt vmcnt(3)" ::: "memory");
  __builtin_amdgcn_s_barrier();

  int s = 0;
  for (int kt = 0; kt < nt; ++kt) {
    const unsigned char* as = As[s];
    const unsigned char* bs = Bs[s];
    int s2 = s + 2; if (s2 >= 3) s2 -= 3;
    bool p2 = kt + 2 < nt;

    l2 av[4], bv[4];
#pragma unroll
    for (int m = 0; m < 4; ++m) av[m] = *(const l2*)&as[(rA0 + m * 16) * 64 + ko];
#pragma unroll
    for (int n = 0; n < 4; ++n) bv[n] = *(const l2*)&bs[(rB0 + n * 16) * 64 + ko];
    if (p2) { stA(kt + 2, s2, 0); stA(kt + 2, s2, 1); stB(kt + 2, s2); }

    asm volatile("s_waitcnt lgkmcnt(0)" ::: "memory");
    __builtin_amdgcn_sched_barrier(0);
    __builtin_amdgcn_s_setprio(1);
#pragma unroll
    for (int m = 0; m < 4; ++m)
#pragma unroll
      for (int n = 0; n < 4; ++n)
        acc[m][n] = __builtin_amdgcn_mfma_f32_16x16x32_fp8_fp8(av[m].x, bv[n].x, acc[m][n], 0, 0, 0);
#pragma unroll
    for (int m = 0; m < 4; ++m)
#pragma unroll
      for (int n = 0; n < 4; ++n)
        acc[m][n] = __builtin_amdgcn_mfma_f32_16x16x32_fp8_fp8(av[m].y, bv[n].y, acc[m][n], 0, 0, 0);
    __builtin_amdgcn_s_setprio(0);

    if (p2) { asm volatile("s_waitcnt vmcnt(3)" ::: "memory"); }
    else    { asm volatile("s_waitcnt vmcnt(0)" ::: "memory"); }
    __builtin_amdgcn_s_barrier();
    s += 1; if (s == 3) s = 0;
  }

#pragma unroll
  for (int m = 0; m < 4; ++m) {
#pragma unroll
    for (int n = 0; n < 4; ++n) {
#pragma unroll
      for (int r = 0; r < 4; ++r) {
        int row = bm0 + wr * 64 + m * 16 + cl * 4 + r;
        int col = bn0 + wc * 64 + n * 16 + frr;
        size_t o = (size_t)row * N + col;
        float v = acc[m][n][r] * oscale + bias[col];
        if (SILU) v = v / (1.0f + __expf(-v));
        if (RESBF) v += bf2f(resb[o]);
        if (OUT_FP8) {
          int e = n * 16 + frr;
          size_t op = (size_t)row * N + bn0 + wc * 64 + ph64(e);
          ((unsigned char*)Cv)[op] = f2fp8(v);
        } else {
          ((float*)Cv)[o] = v;
        }
      }
    }
  }
}

// ---------------------------------------------------------------------------
extern "C" void kernel_launch(void* const* d_in, const int* in_sizes, int n_in,
                              void* d_out, int out_size, void* d_ws, size_t ws_size,
                              hipStream_t stream) {
  const float* x      = (const float*)d_in[0];
  const float* ln_g   = (const float*)d_in[1];
  const float* ln_b   = (const float*)d_in[2];
  const float* fc_w   = (const float*)d_in[3];
  const float* fc_b   = (const float*)d_in[4];
  const float* w1     = (const float*)d_in[5];
  const float* b1     = (const float*)d_in[6];
  const float* w2     = (const float*)d_in[7];
  const float* b2     = (const float*)d_in[8];
  const float* ph_re  = (const float*)d_in[9];
  const float* ph_im  = (const float*)d_in[10];
  const float* phi_re = (const float*)d_in[11];
  const float* phi_im = (const float*)d_in[12];
  const float* lci_re = (const float*)d_in[13];
  const float* lci_im = (const float*)d_in[14];
  float* out = (float*)d_out;

  char* ws = (char*)d_ws;
  const size_t SZ_BF = (size_t)ROWS * D_ * 2;   // 32 MiB
  const size_t SZ_F8 = (size_t)ROWS * D_;       // 16 MiB
  unsigned short* xn_x2 = (unsigned short*)(ws);               // xn; then x2 bf16
  unsigned short* cbuf  = (unsigned short*)(ws + SZ_BF);       // conv out bf16
  unsigned short* xb    = (unsigned short*)(ws + 2 * SZ_BF);   // x bf16 (gemm1 A + residual)
  unsigned char*  x3f8  = (unsigned char*)(ws + 3 * SZ_BF);    // x3 fp8 (16 MiB)
  unsigned char*  h1f8  = (unsigned char*)(ws + 3 * SZ_BF + SZ_F8);  // h1 fp8 (32 MiB)
  char* wp = ws + 3 * SZ_BF + SZ_F8 + (size_t)ROWS * FF_;
  unsigned short* fc_wt = (unsigned short*)(wp);                       // 2 MiB
  unsigned char*  w1t8  = (unsigned char*)(wp + (size_t)D_ * D_ * 2);  // 2 MiB
  unsigned char*  w2t8  = (unsigned char*)(wp + (size_t)D_ * D_ * 2 + (size_t)D_ * FF_);
  float2* rloc  = (float2*)(wp + (size_t)D_ * D_ * 2 + 2 * (size_t)D_ * FF_);
  float2* carry = rloc + (size_t)B_ * CG * D_;

  // weight prep
  transpose_cast<<<dim3(D_ / 32, D_ / 32), 256, 0, stream>>>(fc_w, fc_wt, D_, D_);
  transpose_cast_fp8<<<dim3(FF_ / 32, D_ / 32), 256, 0, stream>>>(w1, w1t8, D_, FF_, 32.0f);
  transpose_cast_fp8<<<dim3(D_ / 32, FF_ / 32), 256, 0, stream>>>(w2, w2t8, FF_, D_, 32.0f);

  // LN1: xn bf16 (conv input) + xb bf16 (gemm1 A + residual)
  ln1_kernel<<<ROWS, 256, 0, stream>>>(x, ln_g, ln_b, xn_x2, xb);

  // conv (chunked scan)
  conv_pass1<<<dim3(D_ / 256, CG, B_), 256, 0, stream>>>(xn_x2, ph_re, ph_im, rloc);
  conv_pass2<<<dim3((B_ * D_) / 256), 256, 0, stream>>>(ph_re, ph_im, rloc, carry);
  conv_pass3<<<dim3(D_ / 256, CG, B_), 256, 0, stream>>>(xn_x2, ph_re, ph_im, phi_re, phi_im,
                                                         lci_re, lci_im, carry, cbuf);

  // x2 = c * silu(x @ fc_w + fc_b) + x   (bf16 gemm BK=32, 2 blocks/CU)
  gemm_bt_gate<<<(ROWS / 256) * (D_ / 128), 512, 0, stream>>>(
      xb, fc_wt, fc_b, cbuf, xb, xn_x2, D_ / 128, 4, D_, D_);

  // x3 = LN(x2) -> fp8 (k-interleaved)
  ln2c_kernel<<<ROWS, 256, 0, stream>>>(xn_x2, ln_g, ln_b, x3f8);

  // h1 = silu(x3 @ (32*w1)/32 + b1) -> fp8 (k-interleaved)
  gemm_f8<1, 0, 1><<<(ROWS / 256) * (FF_ / 128), 512, 0, stream>>>(
      x3f8, w1t8, b1, nullptr, 1.0f / 32.0f, h1f8, FF_ / 128, 4, FF_, D_);

  // out = x2 + h1 @ (32*w2)/32 + b2   (f32 out; residual read bf16)
  gemm_f8<0, 1, 0><<<(ROWS / 256) * (D_ / 128), 512, 0, stream>>>(
      h1f8, w2t8, b2, xn_x2, 1.0f / 32.0f, out, D_ / 128, 2, D_, FF_);
}

// Round 17
// 234.107 us; speedup vs baseline: 1.1512x; 1.0589x over previous
//
#include <hip/hip_runtime.h>
#include <hip/hip_bf16.h>
#include <hip/hip_fp8.h>
#include <cstdint>
#include <cstddef>

#define B_ 4
#define L_ 4096
#define D_ 1024
#define FF_ 2048
#define ROWS (B_ * L_)   // 16384
#define EPS_ 1e-5f
#define CG 64            // conv chunks
#define CC 64            // conv chunk length (L_/CG)

typedef __attribute__((ext_vector_type(8))) __bf16 bf16x8;
typedef __attribute__((ext_vector_type(4))) float f32x4;
typedef __attribute__((ext_vector_type(16))) float f32x16;
typedef __attribute__((ext_vector_type(4))) unsigned short us4;
typedef __attribute__((ext_vector_type(4))) int i32x4;
typedef __attribute__((ext_vector_type(8))) int i32x8;

#if __has_builtin(__builtin_amdgcn_mfma_scale_f32_32x32x64_f8f6f4)
#define HAS_MX 1
#else
#define HAS_MX 0
#endif

__device__ __forceinline__ float bf2f(unsigned short u) {
  union { unsigned int i; float f; } v; v.i = ((unsigned int)u) << 16; return v.f;
}
__device__ __forceinline__ unsigned short f2bf(float f) {
  union { float f; unsigned int i; } v; v.f = f;
  unsigned int r = v.i + 0x7fffu + ((v.i >> 16) & 1u);
  return (unsigned short)(r >> 16);
}
__device__ __forceinline__ unsigned char f2fp8(float f) {
  __hip_fp8_e4m3 q(f);
  return *reinterpret_cast<unsigned char*>(&q);
}

// ---------------- weight transpose + cast: in [K,N] f32 -> out [N,K] bf16 ----
__global__ __launch_bounds__(256) void transpose_cast(
    const float* __restrict__ in, unsigned short* __restrict__ out, int K, int N) {
  __shared__ float tb[32][33];
  int n0 = blockIdx.x * 32, k0 = blockIdx.y * 32;
  int tx = threadIdx.x & 31, ty = threadIdx.x >> 5;  // 32 x 8
#pragma unroll
  for (int i = 0; i < 4; ++i) {
    int k = ty + i * 8;
    tb[k][tx] = in[(size_t)(k0 + k) * N + n0 + tx];
  }
  __syncthreads();
#pragma unroll
  for (int i = 0; i < 4; ++i) {
    int n = ty + i * 8;
    out[(size_t)(n0 + n) * K + k0 + tx] = f2bf(tb[tx][n]);
  }
}

// -------- weight transpose + cast fp8 (natural k order): [K,N] -> [N,K] ------
__global__ __launch_bounds__(256) void transpose_cast_fp8(
    const float* __restrict__ in, unsigned char* __restrict__ out, int K, int N,
    float scale) {
  __shared__ float tb[32][33];
  int n0 = blockIdx.x * 32, k0 = blockIdx.y * 32;
  int tx = threadIdx.x & 31, ty = threadIdx.x >> 5;
#pragma unroll
  for (int i = 0; i < 4; ++i) {
    int k = ty + i * 8;
    tb[k][tx] = in[(size_t)(k0 + k) * N + n0 + tx];
  }
  __syncthreads();
#pragma unroll
  for (int i = 0; i < 4; ++i) {
    int n = ty + i * 8;
    out[(size_t)(n0 + n) * K + k0 + tx] = f2fp8(tb[tx][n] * scale);
  }
}

// ---------------- LN1: x -> xn bf16 (LayerNorm), xb bf16 (plain cast) --------
__global__ __launch_bounds__(256) void ln1_kernel(
    const float* __restrict__ x, const float* __restrict__ g, const float* __restrict__ b,
    unsigned short* __restrict__ xn, unsigned short* __restrict__ xb) {
  int row = blockIdx.x;
  int t = threadIdx.x;
  const float4* xr = (const float4*)(x + (size_t)row * D_);
  float4 v = xr[t];
  float s = v.x + v.y + v.z + v.w;
  float sq = v.x * v.x + v.y * v.y + v.z * v.z + v.w * v.w;
#pragma unroll
  for (int off = 32; off > 0; off >>= 1) {
    s += __shfl_down(s, off);
    sq += __shfl_down(sq, off);
  }
  __shared__ float ls[4], lq[4];
  int lane = t & 63, w = t >> 6;
  if (lane == 0) { ls[w] = s; lq[w] = sq; }
  __syncthreads();
  s = ls[0] + ls[1] + ls[2] + ls[3];
  sq = lq[0] + lq[1] + lq[2] + lq[3];
  float mean = s * (1.0f / D_);
  float var = sq * (1.0f / D_) - mean * mean;
  float rstd = rsqrtf(var + EPS_);
  float4 gv = ((const float4*)g)[t];
  float4 bv = ((const float4*)b)[t];
  us4 o, ob;
  o.x = f2bf((v.x - mean) * rstd * gv.x + bv.x);
  o.y = f2bf((v.y - mean) * rstd * gv.y + bv.y);
  o.z = f2bf((v.z - mean) * rstd * gv.z + bv.z);
  o.w = f2bf((v.w - mean) * rstd * gv.w + bv.w);
  ob.x = f2bf(v.x); ob.y = f2bf(v.y); ob.z = f2bf(v.z); ob.w = f2bf(v.w);
  ((us4*)(xn + (size_t)row * D_))[t] = o;
  ((us4*)(xb + (size_t)row * D_))[t] = ob;
}

// ---------------- conv pass 1: per-chunk local recurrence --------------------
__global__ __launch_bounds__(256) void conv_pass1(
    const unsigned short* __restrict__ xn, const float* __restrict__ ph_re,
    const float* __restrict__ ph_im, float2* __restrict__ rloc) {
  int d = blockIdx.x * 256 + threadIdx.x;
  int g = blockIdx.y, b = blockIdx.z;
  float re = ph_re[d], im = ph_im[d];
  float a = sqrtf(re * re + im * im);
  float sc = expf(-a) / a;
  float pr = re * sc, pi = im * sc;
  float rr = 0.f, ri = 0.f;
  const unsigned short* xp = xn + ((size_t)(b * L_ + g * CC)) * D_ + d;
#pragma unroll 8
  for (int l = 0; l < CC; ++l) {
    float xv = bf2f(xp[(size_t)l * D_]);
    float nr = pr * rr - pi * ri + xv;
    ri = pr * ri + pi * rr;
    rr = nr;
  }
  rloc[((size_t)(b * CG + g)) * D_ + d] = make_float2(rr, ri);
}

// ---------------- conv pass 2: scan over chunks (batch-8 prefetched) ---------
__global__ __launch_bounds__(256) void conv_pass2(
    const float* __restrict__ ph_re, const float* __restrict__ ph_im,
    const float2* __restrict__ rloc, float2* __restrict__ carry) {
  int idx = blockIdx.x * 256 + threadIdx.x;  // 0..B*D-1
  int b = idx >> 10, d = idx & (D_ - 1);
  float re = ph_re[d], im = ph_im[d];
  float a = sqrtf(re * re + im * im);
  float th = atan2f(im, re);
  float rho = expf(-a * (float)CC);
  float ang = th * (float)CC;
  float pcr = rho * cosf(ang), pci = rho * sinf(ang);
  float cr = 0.f, ci = 0.f;
  for (int g0 = 0; g0 < CG; g0 += 8) {
    float2 rl[8];
    float2 cw[8];
#pragma unroll
    for (int i = 0; i < 8; ++i)
      rl[i] = rloc[((size_t)(b * CG + g0 + i)) * D_ + d];
#pragma unroll
    for (int i = 0; i < 8; ++i) {
      cw[i] = make_float2(cr, ci);
      float nr = pcr * cr - pci * ci + rl[i].x;
      ci = pcr * ci + pci * cr + rl[i].y;
      cr = nr;
    }
#pragma unroll
    for (int i = 0; i < 8; ++i)
      carry[((size_t)(b * CG + g0 + i)) * D_ + d] = cw[i];
  }
}

// ---------------- conv pass 3: outputs -------------------------------------
__global__ __launch_bounds__(256) void conv_pass3(
    const unsigned short* __restrict__ xn,
    const float* __restrict__ ph_re, const float* __restrict__ ph_im,
    const float* __restrict__ phi_re, const float* __restrict__ phi_im,
    const float* __restrict__ lci_re, const float* __restrict__ lci_im,
    const float2* __restrict__ carry, unsigned short* __restrict__ cout) {
  int d = blockIdx.x * 256 + threadIdx.x;
  int g = blockIdx.y, b = blockIdx.z;
  float re = ph_re[d], im = ph_im[d];
  float a = sqrtf(re * re + im * im);
  float sc = expf(-a) / a;
  float pr = re * sc, pi = im * sc;
  float th = atan2f(im, re);
  int l0 = g * CC;
  float rho = expf(-a * (float)(l0 + 1));
  float ang = th * (float)(l0 + 1);
  float prr = rho * cosf(ang), pri = rho * sinf(ang);
  float fr = phi_re[d], fi = phi_im[d];
  float qr = lci_re[d], qi = lci_im[d];
  float2 cv = carry[((size_t)(b * CG + g)) * D_ + d];
  float rr = cv.x, ri = cv.y;
  const unsigned short* xp = xn + ((size_t)(b * L_ + l0)) * D_ + d;
  unsigned short* cp = cout + ((size_t)(b * L_ + l0)) * D_ + d;
#pragma unroll 4
  for (int l = 0; l < CC; ++l) {
    float xv = bf2f(xp[(size_t)l * D_]);
    float nr = pr * rr - pi * ri + xv;
    ri = pr * ri + pi * rr;
    rr = nr;
    float outv = fr * rr - fi * ri + qr * prr - qi * pri;  // Re(phi*r + lci*p)
    cp[(size_t)l * D_] = f2bf(outv);
    float pn = pr * prr - pi * pri;
    pri = pr * pri + pi * prr;
    prr = pn;
  }
}

// ------- LN2c: x3 = LN(x2 bf16) -> fp8 e4m3 (natural k order) ---------------
__global__ __launch_bounds__(256) void ln2c_kernel(
    const unsigned short* __restrict__ x2, const float* __restrict__ g,
    const float* __restrict__ b, unsigned char* __restrict__ x3) {
  int row = blockIdx.x;
  int t = threadIdx.x;
  size_t base = (size_t)row * D_;
  us4 vb = ((const us4*)(x2 + base))[t];
  float4 v;
  v.x = bf2f(vb.x); v.y = bf2f(vb.y); v.z = bf2f(vb.z); v.w = bf2f(vb.w);
  float s = v.x + v.y + v.z + v.w;
  float sq = v.x * v.x + v.y * v.y + v.z * v.z + v.w * v.w;
#pragma unroll
  for (int off = 32; off > 0; off >>= 1) {
    s += __shfl_down(s, off);
    sq += __shfl_down(sq, off);
  }
  __shared__ float ls[4], lq[4];
  int lane = t & 63, w = t >> 6;
  if (lane == 0) { ls[w] = s; lq[w] = sq; }
  __syncthreads();
  s = ls[0] + ls[1] + ls[2] + ls[3];
  sq = lq[0] + lq[1] + lq[2] + lq[3];
  float mean = s * (1.0f / D_);
  float var = sq * (1.0f / D_) - mean * mean;
  float rstd = rsqrtf(var + EPS_);
  float4 gv = ((const float4*)g)[t];
  float4 bv = ((const float4*)b)[t];
  uchar4 o;
  o.x = f2fp8((v.x - mean) * rstd * gv.x + bv.x);
  o.y = f2fp8((v.y - mean) * rstd * gv.y + bv.y);
  o.z = f2fp8((v.z - mean) * rstd * gv.z + bv.z);
  o.w = f2fp8((v.w - mean) * rstd * gv.w + bv.w);
  ((uchar4*)(x3 + base))[t] = o;
}

// ============================================================================
__device__ __forceinline__ void gld_lds16(const void* gp, void* lp) {
  __builtin_amdgcn_global_load_lds(
      (const __attribute__((address_space(1))) unsigned int*)gp,
      (__attribute__((address_space(3))) unsigned int*)lp, 16, 0, 0);
}

// ------- bf16 GEMM, BK=32, 2 blocks/CU (gemm1) -- UNCHANGED from R16 --------
__global__ __launch_bounds__(512, 4) void gemm_bt_gate(
    const unsigned short* __restrict__ A, const unsigned short* __restrict__ Bt,
    const float* __restrict__ bias,
    const unsigned short* __restrict__ gate, const unsigned short* __restrict__ xresb,
    unsigned short* __restrict__ Cv, int NB, int GROUP, int N, int K) {
  __shared__ unsigned short As[3][256 * 32];  // 3 x 16 KiB
  __shared__ unsigned short Bs[3][128 * 32];  // 3 x 8 KiB

  int nwg = gridDim.x;
  int xcd = blockIdx.x & 7;
  int lo = blockIdx.x >> 3;
  int q = nwg >> 3;
  int gsz = GROUP * NB;
  int g_ = lo / gsz, r_ = lo % gsz;
  int n_ = r_ / GROUP, ml = r_ - n_ * GROUP;
  int Mx = q / NB;
  int bm0 = (xcd * Mx + g_ * GROUP + ml) * 256;
  int bn0 = n_ * 128;

  int t = threadIdx.x;
  int lane = t & 63, w = t >> 6;
  int wr = w >> 1, wc = w & 1;
  int frr = lane & 15, cl = lane >> 4;
  int sw = (frr >> 1) & 3;
  int rA0 = wr * 64 + frr;
  int rB0 = wc * 64 + frr;
  int ko = (cl ^ sw) * 8;

  int nt = K >> 5;

  int tr = t >> 2;
  int jc = (t & 3) ^ ((tr >> 1) & 3);
  const unsigned short* pA = A + (size_t)(bm0 + tr) * K + jc * 8;
  const unsigned short* pB = Bt + (size_t)(bn0 + tr) * K + jc * 8;

  auto stA = [&](int kt2, int slot, int c) {
    gld_lds16(pA + (size_t)kt2 * 32 + (size_t)c * 128 * K, &As[slot][c * 4096 + t * 8]);
  };
  auto stB = [&](int kt2, int slot) {
    gld_lds16(pB + (size_t)kt2 * 32, &Bs[slot][t * 8]);
  };

  f32x4 acc[4][4] = {};

  stA(0, 0, 0); stA(0, 0, 1); stB(0, 0);
  stA(1, 1, 0); stA(1, 1, 1); stB(1, 1);
  asm volatile("s_waitcnt vmcnt(3)" ::: "memory");
  __builtin_amdgcn_s_barrier();

  int s = 0;
  for (int kt = 0; kt < nt; ++kt) {
    const unsigned short* as = As[s];
    const unsigned short* bs = Bs[s];
    int s2 = s + 2; if (s2 >= 3) s2 -= 3;
    bool p2 = kt + 2 < nt;

    bf16x8 av[4], bv[4];
#pragma unroll
    for (int m = 0; m < 4; ++m) av[m] = *(const bf16x8*)&as[(rA0 + m * 16) * 32 + ko];
#pragma unroll
    for (int n = 0; n < 4; ++n) bv[n] = *(const bf16x8*)&bs[(rB0 + n * 16) * 32 + ko];
    if (p2) { stA(kt + 2, s2, 0); stA(kt + 2, s2, 1); stB(kt + 2, s2); }

    asm volatile("s_waitcnt lgkmcnt(0)" ::: "memory");
    __builtin_amdgcn_sched_barrier(0);
    __builtin_amdgcn_s_setprio(1);
#pragma unroll
    for (int m = 0; m < 4; ++m)
#pragma unroll
      for (int n = 0; n < 4; ++n)
        acc[m][n] = __builtin_amdgcn_mfma_f32_16x16x32_bf16(av[m], bv[n], acc[m][n], 0, 0, 0);
    __builtin_amdgcn_s_setprio(0);

    if (p2) { asm volatile("s_waitcnt vmcnt(3)" ::: "memory"); }
    else    { asm volatile("s_waitcnt vmcnt(0)" ::: "memory"); }
    __builtin_amdgcn_s_barrier();
    s += 1; if (s == 3) s = 0;
  }

#pragma unroll
  for (int m = 0; m < 4; ++m) {
#pragma unroll
    for (int n = 0; n < 4; ++n) {
#pragma unroll
      for (int r = 0; r < 4; ++r) {
        int row = bm0 + wr * 64 + m * 16 + cl * 4 + r;
        int col = bn0 + wc * 64 + n * 16 + frr;
        size_t o = (size_t)row * N + col;
        float v = acc[m][n][r] + bias[col];
        v = v / (1.0f + __expf(-v));
        v = bf2f(gate[o]) * v + bf2f(xresb[o]);
        Cv[o] = f2bf(v);
      }
    }
  }
}

// ------- fp8 GEMM: MX-scaled 32x32x64 (scale=1.0), natural k order ----------
// BM=256, BN=128, BK=64, 8 waves (4Mx2N), ring-3 = 72 KiB -> 2 blocks/CU.
// Staging identical to R16 (proven): LDS block (row,k16) at row*4 +
// (k16 ^ ((row>>1)&3)). 32x32x64 fragment: row=lane&31, k=32*(lane>>5)+e ->
// two b128 reads at k16 = {2h, 2h+1} ^ sw; quarter-wave = 16 consecutive
// rows at one k16 -> exact 2-way (free). 4 MFMA/wave/tile (vs 32 at 16x16).
// C/D 32x32: col=lane&31, row=(rg&3)+8*(rg>>2)+4*(lane>>5)  [m74/m101].
// Sync skeleton identical to R16's proven single-phase loop.
template <int SILU, int RESBF, int OUT_FP8>
__global__ __launch_bounds__(512, 4) void gemm_f8(
    const unsigned char* __restrict__ A, const unsigned char* __restrict__ Bt,
    const float* __restrict__ bias, const unsigned short* __restrict__ resb,
    float oscale, void* __restrict__ Cv, int NB, int GROUP, int N, int K) {
  __shared__ unsigned char As[3][256 * 64];  // 3 x 16 KiB
  __shared__ unsigned char Bs[3][128 * 64];  // 3 x 8 KiB

  int nwg = gridDim.x;
  int xcd = blockIdx.x & 7;
  int lo = blockIdx.x >> 3;
  int q = nwg >> 3;
  int gsz = GROUP * NB;
  int g_ = lo / gsz, r_ = lo % gsz;
  int n_ = r_ / GROUP, ml = r_ - n_ * GROUP;
  int Mx = q / NB;
  int bm0 = (xcd * Mx + g_ * GROUP + ml) * 256;
  int bn0 = n_ * 128;

  int t = threadIdx.x;
  int lane = t & 63, w = t >> 6;
  int wr = w >> 1, wc = w & 1;          // 4M x 2N

  int nt = K >> 6;  // K-tiles of 64 fp8

  // staging (R16-proven): 128 rows/call; thread t -> row t>>2, global chunk jc
  int tr = t >> 2;
  int jc = (t & 3) ^ ((tr >> 1) & 3);
  const unsigned char* pA = A + (size_t)(bm0 + tr) * K + jc * 16;
  const unsigned char* pB = Bt + (size_t)(bn0 + tr) * K + jc * 16;

  auto stA = [&](int kt2, int slot, int c) {  // c=0: rows 0-127, c=1: 128-255
    gld_lds16(pA + (size_t)kt2 * 64 + (size_t)c * 128 * K, &As[slot][c * 8192 + t * 16]);
  };
  auto stB = [&](int kt2, int slot) {
    gld_lds16(pB + (size_t)kt2 * 64, &Bs[slot][t * 16]);
  };

#if HAS_MX
  int l31 = lane & 31, h = lane >> 5;
  int rA0 = wr * 64 + l31;              // + mi*32
  int rB0 = wc * 64 + l31;              // + ni*32
  f32x16 acc[2][2] = {};
#else
  int frr = lane & 15, cl = lane >> 4;
  int rA0 = wr * 64 + frr;
  int rB0 = wc * 64 + frr;
  f32x4 acc[4][4] = {};
#endif

  stA(0, 0, 0); stA(0, 0, 1); stB(0, 0);
  stA(1, 1, 0); stA(1, 1, 1); stB(1, 1);
  asm volatile("s_waitcnt vmcnt(3)" ::: "memory");
  __builtin_amdgcn_s_barrier();

  int s = 0;
  for (int kt = 0; kt < nt; ++kt) {
    const unsigned char* as = As[s];
    const unsigned char* bs = Bs[s];
    int s2 = s + 2; if (s2 >= 3) s2 -= 3;
    bool p2 = kt + 2 < nt;

#if HAS_MX
    i32x8 av[2], bv[2];
#pragma unroll
    for (int mi = 0; mi < 2; ++mi) {
      int r = rA0 + mi * 32;
      int swr = (r >> 1) & 3;
      const unsigned char* bp = &as[r * 64];
      i32x4 lo4 = *(const i32x4*)&bp[((2 * h) ^ swr) * 16];
      i32x4 hi4 = *(const i32x4*)&bp[((2 * h + 1) ^ swr) * 16];
      av[mi] = __builtin_shufflevector(lo4, hi4, 0, 1, 2, 3, 4, 5, 6, 7);
    }
#pragma unroll
    for (int ni = 0; ni < 2; ++ni) {
      int r = rB0 + ni * 32;
      int swr = (r >> 1) & 3;
      const unsigned char* bp = &bs[r * 64];
      i32x4 lo4 = *(const i32x4*)&bp[((2 * h) ^ swr) * 16];
      i32x4 hi4 = *(const i32x4*)&bp[((2 * h + 1) ^ swr) * 16];
      bv[ni] = __builtin_shufflevector(lo4, hi4, 0, 1, 2, 3, 4, 5, 6, 7);
    }
    if (p2) { stA(kt + 2, s2, 0); stA(kt + 2, s2, 1); stB(kt + 2, s2); }

    asm volatile("s_waitcnt lgkmcnt(0)" ::: "memory");
    __builtin_amdgcn_sched_barrier(0);
    __builtin_amdgcn_s_setprio(1);
#pragma unroll
    for (int mi = 0; mi < 2; ++mi)
#pragma unroll
      for (int ni = 0; ni < 2; ++ni)
        acc[mi][ni] = __builtin_amdgcn_mfma_scale_f32_32x32x64_f8f6f4(
            av[mi], bv[ni], acc[mi][ni], 0, 0, 0, 0x7F, 0, 0x7F);
    __builtin_amdgcn_s_setprio(0);
#else
    long a0[4], b0[4], a1[4], b1[4];
#pragma unroll
    for (int m = 0; m < 4; ++m) {
      int r = rA0 + m * 16;
      int swr = (r >> 1) & 3;
      const unsigned char* bp = &as[r * 64];
      a0[m] = *(const long*)&bp[((cl >> 1) ^ swr) * 16 + (cl & 1) * 8];
      a1[m] = *(const long*)&bp[(((cl + 4) >> 1) ^ swr) * 16 + (cl & 1) * 8];
    }
#pragma unroll
    for (int n = 0; n < 4; ++n) {
      int r = rB0 + n * 16;
      int swr = (r >> 1) & 3;
      const unsigned char* bp = &bs[r * 64];
      b0[n] = *(const long*)&bp[((cl >> 1) ^ swr) * 16 + (cl & 1) * 8];
      b1[n] = *(const long*)&bp[(((cl + 4) >> 1) ^ swr) * 16 + (cl & 1) * 8];
    }
    if (p2) { stA(kt + 2, s2, 0); stA(kt + 2, s2, 1); stB(kt + 2, s2); }

    asm volatile("s_waitcnt lgkmcnt(0)" ::: "memory");
    __builtin_amdgcn_sched_barrier(0);
    __builtin_amdgcn_s_setprio(1);
#pragma unroll
    for (int m = 0; m < 4; ++m)
#pragma unroll
      for (int n = 0; n < 4; ++n)
        acc[m][n] = __builtin_amdgcn_mfma_f32_16x16x32_fp8_fp8(a0[m], b0[n], acc[m][n], 0, 0, 0);
#pragma unroll
    for (int m = 0; m < 4; ++m)
#pragma unroll
      for (int n = 0; n < 4; ++n)
        acc[m][n] = __builtin_amdgcn_mfma_f32_16x16x32_fp8_fp8(a1[m], b1[n], acc[m][n], 0, 0, 0);
    __builtin_amdgcn_s_setprio(0);
#endif

    if (p2) { asm volatile("s_waitcnt vmcnt(3)" ::: "memory"); }
    else    { asm volatile("s_waitcnt vmcnt(0)" ::: "memory"); }
    __builtin_amdgcn_s_barrier();
    s += 1; if (s == 3) s = 0;
  }

#if HAS_MX
  // epilogue (32x32 C layout: col=lane&31, row=(rg&3)+8*(rg>>2)+4*(lane>>5))
#pragma unroll
  for (int mi = 0; mi < 2; ++mi) {
#pragma unroll
    for (int ni = 0; ni < 2; ++ni) {
#pragma unroll
      for (int rg = 0; rg < 16; ++rg) {
        int row = bm0 + wr * 64 + mi * 32 + (rg & 3) + 8 * (rg >> 2) + 4 * h;
        int col = bn0 + wc * 64 + ni * 32 + l31;
        size_t o = (size_t)row * N + col;
        float v = acc[mi][ni][rg] * oscale + bias[col];
        if (SILU) v = v / (1.0f + __expf(-v));
        if (RESBF) v += bf2f(resb[o]);
        if (OUT_FP8) ((unsigned char*)Cv)[o] = f2fp8(v);
        else         ((float*)Cv)[o] = v;
      }
    }
  }
#else
  // epilogue (16x16 C layout)
#pragma unroll
  for (int m = 0; m < 4; ++m) {
#pragma unroll
    for (int n = 0; n < 4; ++n) {
#pragma unroll
      for (int r = 0; r < 4; ++r) {
        int row = bm0 + wr * 64 + m * 16 + cl * 4 + r;
        int col = bn0 + wc * 64 + n * 16 + frr;
        size_t o = (size_t)row * N + col;
        float v = acc[m][n][r] * oscale + bias[col];
        if (SILU) v = v / (1.0f + __expf(-v));
        if (RESBF) v += bf2f(resb[o]);
        if (OUT_FP8) ((unsigned char*)Cv)[o] = f2fp8(v);
        else         ((float*)Cv)[o] = v;
      }
    }
  }
#endif
}

// ---------------------------------------------------------------------------
extern "C" void kernel_launch(void* const* d_in, const int* in_sizes, int n_in,
                              void* d_out, int out_size, void* d_ws, size_t ws_size,
                              hipStream_t stream) {
  const float* x      = (const float*)d_in[0];
  const float* ln_g   = (const float*)d_in[1];
  const float* ln_b   = (const float*)d_in[2];
  const float* fc_w   = (const float*)d_in[3];
  const float* fc_b   = (const float*)d_in[4];
  const float* w1     = (const float*)d_in[5];
  const float* b1     = (const float*)d_in[6];
  const float* w2     = (const float*)d_in[7];
  const float* b2     = (const float*)d_in[8];
  const float* ph_re  = (const float*)d_in[9];
  const float* ph_im  = (const float*)d_in[10];
  const float* phi_re = (const float*)d_in[11];
  const float* phi_im = (const float*)d_in[12];
  const float* lci_re = (const float*)d_in[13];
  const float* lci_im = (const float*)d_in[14];
  float* out = (float*)d_out;

  char* ws = (char*)d_ws;
  const size_t SZ_BF = (size_t)ROWS * D_ * 2;   // 32 MiB
  const size_t SZ_F8 = (size_t)ROWS * D_;       // 16 MiB
  unsigned short* xn_x2 = (unsigned short*)(ws);               // xn; then x2 bf16
  unsigned short* cbuf  = (unsigned short*)(ws + SZ_BF);       // conv out bf16
  unsigned short* xb    = (unsigned short*)(ws + 2 * SZ_BF);   // x bf16 (gemm1 A + residual)
  unsigned char*  x3f8  = (unsigned char*)(ws + 3 * SZ_BF);    // x3 fp8 (16 MiB)
  unsigned char*  h1f8  = (unsigned char*)(ws + 3 * SZ_BF + SZ_F8);  // h1 fp8 (32 MiB)
  char* wp = ws + 3 * SZ_BF + SZ_F8 + (size_t)ROWS * FF_;
  unsigned short* fc_wt = (unsigned short*)(wp);                       // 2 MiB
  unsigned char*  w1t8  = (unsigned char*)(wp + (size_t)D_ * D_ * 2);  // 2 MiB
  unsigned char*  w2t8  = (unsigned char*)(wp + (size_t)D_ * D_ * 2 + (size_t)D_ * FF_);
  float2* rloc  = (float2*)(wp + (size_t)D_ * D_ * 2 + 2 * (size_t)D_ * FF_);
  float2* carry = rloc + (size_t)B_ * CG * D_;

  // weight prep
  transpose_cast<<<dim3(D_ / 32, D_ / 32), 256, 0, stream>>>(fc_w, fc_wt, D_, D_);
  transpose_cast_fp8<<<dim3(FF_ / 32, D_ / 32), 256, 0, stream>>>(w1, w1t8, D_, FF_, 32.0f);
  transpose_cast_fp8<<<dim3(D_ / 32, FF_ / 32), 256, 0, stream>>>(w2, w2t8, FF_, D_, 32.0f);

  // LN1: xn bf16 (conv input) + xb bf16 (gemm1 A + residual)
  ln1_kernel<<<ROWS, 256, 0, stream>>>(x, ln_g, ln_b, xn_x2, xb);

  // conv (chunked scan)
  conv_pass1<<<dim3(D_ / 256, CG, B_), 256, 0, stream>>>(xn_x2, ph_re, ph_im, rloc);
  conv_pass2<<<dim3((B_ * D_) / 256), 256, 0, stream>>>(ph_re, ph_im, rloc, carry);
  conv_pass3<<<dim3(D_ / 256, CG, B_), 256, 0, stream>>>(xn_x2, ph_re, ph_im, phi_re, phi_im,
                                                         lci_re, lci_im, carry, cbuf);

  // x2 = c * silu(x @ fc_w + fc_b) + x   (bf16 gemm BK=32, 2 blocks/CU)
  gemm_bt_gate<<<(ROWS / 256) * (D_ / 128), 512, 0, stream>>>(
      xb, fc_wt, fc_b, cbuf, xb, xn_x2, D_ / 128, 4, D_, D_);

  // x3 = LN(x2) -> fp8 (natural)
  ln2c_kernel<<<ROWS, 256, 0, stream>>>(xn_x2, ln_g, ln_b, x3f8);

  // h1 = silu(x3 @ (32*w1)/32 + b1) -> fp8 (natural)
  gemm_f8<1, 0, 1><<<(ROWS / 256) * (FF_ / 128), 512, 0, stream>>>(
      x3f8, w1t8, b1, nullptr, 1.0f / 32.0f, h1f8, FF_ / 128, 4, FF_, D_);

  // out = x2 + h1 @ (32*w2)/32 + b2   (f32 out; residual read bf16)
  gemm_f8<0, 1, 0><<<(ROWS / 256) * (D_ / 128), 512, 0, stream>>>(
      h1f8, w2t8, b2, xn_x2, 1.0f / 32.0f, out, D_ / 128, 2, D_, FF_);
}